// Round 2
// baseline (765.046 us; speedup 1.0000x reference)
//
#include <hip/hip_runtime.h>
#include <hip/hip_bf16.h>
#include <math.h>

#define B_SZ 4
#define T_LEN 8192
#define C_IN 7
#define NPATCH 1023
#define DIM 512
#define NH 8
#define HD 64
#define NLAYERS 4
#define MLP_HID 2048
#define M_ROWS (B_SZ * NPATCH)   // 4092
#define KEMB 128                 // padded patch length (112 real + 16 zero)
#define LN_EPS 1e-5f
#define NSPLIT 2
#define KCHUNK 512               // keys per split chunk

typedef __attribute__((ext_vector_type(8))) short short8;
typedef __attribute__((ext_vector_type(4))) float float4v;

static __device__ __forceinline__ unsigned short f2bf(float f) {
  __hip_bfloat16 h = __float2bfloat16(f);
  return *reinterpret_cast<unsigned short*>(&h);
}
static __device__ __forceinline__ float bf2f(unsigned short u) {
  return __uint_as_float(((unsigned)u) << 16);
}

// ---------------------------------------------------------------------------
// Patch gather: Pm[row][c*16+p] = bf16(x[b, i*8+p, c]); cols 112..127 = 0.
// ---------------------------------------------------------------------------
__global__ __launch_bounds__(256) void patch_kernel(
    const float* __restrict__ x, unsigned short* __restrict__ Pm) {
  int idx = blockIdx.x * 256 + threadIdx.x;
  if (idx >= M_ROWS * KEMB) return;
  int row = idx >> 7, c = idx & 127;
  float v = 0.f;
  if (c < 112) {
    int b = row / NPATCH, i = row - b * NPATCH;
    int ci = c >> 4, p = c & 15;
    v = x[((size_t)b * T_LEN + (size_t)i * 8 + p) * C_IN + ci];
  }
  Pm[idx] = f2bf(v);
}

// ---------------------------------------------------------------------------
// W_emb convert: Wt[n][k] = bf16(W_emb[k][n]) for k<112, 0 for k in [112,128).
// ---------------------------------------------------------------------------
__global__ __launch_bounds__(256) void wemb_cvt_kernel(
    const float* __restrict__ W, unsigned short* __restrict__ Wt) {
  int idx = blockIdx.x * 256 + threadIdx.x;
  if (idx >= DIM * KEMB) return;
  int n = idx >> 7, k = idx & 127;
  float v = (k < 112) ? W[(size_t)k * DIM + n] : 0.f;
  Wt[idx] = f2bf(v);
}

// ---------------------------------------------------------------------------
// LayerNorm, 4 rows/block. BF: bf16 vs fp32 out.
// ---------------------------------------------------------------------------
template <bool BF>
__global__ __launch_bounds__(256) void ln_kernel(
    const float* __restrict__ in, const float* __restrict__ g,
    const float* __restrict__ bb, void* __restrict__ outv, int M) {
  int row = blockIdx.x * 4 + (threadIdx.x >> 6);
  if (row >= M) return;
  int lane = threadIdx.x & 63;
  const float* xr = in + (size_t)row * DIM;
  float v[8];
  float s = 0.f;
  #pragma unroll
  for (int k = 0; k < 8; ++k) { v[k] = xr[lane + 64 * k]; s += v[k]; }
  #pragma unroll
  for (int off = 32; off; off >>= 1) s += __shfl_down(s, off);
  s = __shfl(s, 0);
  float mu = s * (1.f / DIM);
  float q = 0.f;
  #pragma unroll
  for (int k = 0; k < 8; ++k) { float d = v[k] - mu; q = fmaf(d, d, q); }
  #pragma unroll
  for (int off = 32; off; off >>= 1) q += __shfl_down(q, off);
  q = __shfl(q, 0);
  float rstd = rsqrtf(q * (1.f / DIM) + LN_EPS);
  #pragma unroll
  for (int k = 0; k < 8; ++k) {
    int d = lane + 64 * k;
    float r = (v[k] - mu) * rstd * g[d] + bb[d];
    if (BF)
      ((unsigned short*)outv)[(size_t)row * DIM + d] = f2bf(r);
    else
      ((float*)outv)[(size_t)row * DIM + d] = r;
  }
}

// ---------------------------------------------------------------------------
// Weight convert + transpose: W[K][N] fp32 -> Wt[N][K] bf16 (per layer z).
// ---------------------------------------------------------------------------
__global__ __launch_bounds__(256) void wcvt_kernel(
    const float* __restrict__ W, unsigned short* __restrict__ Wt, int K, int N) {
  __shared__ float tile[32][33];
  int n0 = blockIdx.x * 32, k0 = blockIdx.y * 32, L = blockIdx.z;
  const float* Ws = W + (size_t)L * K * N;
  unsigned short* Wd = Wt + (size_t)L * K * N;
  int tx = threadIdx.x & 31, ty = threadIdx.x >> 5;
  #pragma unroll
  for (int i = 0; i < 4; ++i)
    tile[ty + i * 8][tx] = Ws[(size_t)(k0 + ty + i * 8) * N + n0 + tx];
  __syncthreads();
  #pragma unroll
  for (int i = 0; i < 4; ++i)
    Wd[(size_t)(n0 + ty + i * 8) * K + k0 + tx] = f2bf(tile[tx][ty + i * 8]);
}

// ---------------------------------------------------------------------------
// RoPE cos/sin table: tab[i*32+j] = (cos, sin) of i * 10000^(-j/32).
// ---------------------------------------------------------------------------
__global__ __launch_bounds__(256) void rope_tab_kernel(float2* __restrict__ tab) {
  int idx = blockIdx.x * 256 + threadIdx.x;
  if (idx >= NPATCH * 32) return;
  int i = idx >> 5, j = idx & 31;
  float inv = powf(10000.0f, -(float)j * (1.0f / 32.0f));
  float sn, cs;
  sincosf((float)i * inv, &sn, &cs);
  tab[idx] = make_float2(cs, sn);
}

// ---------------------------------------------------------------------------
// bf16 MFMA GEMM, TM x TN tile, BK=32, 4 waves (2x2), double-buffered LDS,
// ONE barrier per K-iter. EPI codes as before.
// ---------------------------------------------------------------------------
template <int TM, int TN, int EPI>
__global__ __launch_bounds__(256) void mfma_gemm(
    const unsigned short* __restrict__ A, const unsigned short* __restrict__ Bt,
    const float* __restrict__ bias, const float* __restrict__ res,
    float* __restrict__ Cf, float* __restrict__ Cf2,
    unsigned short* __restrict__ Cb, const float2* __restrict__ rtab,
    int M, int N, int K) {
  constexpr int WM = TM / 2, WN = TN / 2;
  constexpr int NI = WM / 16, NJ = WN / 16;
  constexpr int ACH = TM * 4;               // A uint4 chunks per K-tile
  constexpr int TCH = (TM + TN) * 4;        // total chunks
  constexpr int CH = TCH / 256;             // chunks per thread
  __shared__ __align__(16) unsigned short As[2][TM][40];
  __shared__ __align__(16) unsigned short Bs[2][TN][40];
  const int bm = blockIdx.y * TM;
  const int bn = blockIdx.x * TN;
  const int tid = threadIdx.x;
  const int lane = tid & 63, wave = tid >> 6;
  const int quad = lane >> 4, l16 = lane & 15;
  const int wm = (wave & 1) * WM;
  const int wn = (wave >> 1) * WN;

  float4v acc[NI][NJ];
  #pragma unroll
  for (int i = 0; i < NI; ++i)
    #pragma unroll
    for (int j = 0; j < NJ; ++j)
      acc[i][j] = (float4v){0.f, 0.f, 0.f, 0.f};

  uint4 pr[CH];
  auto load_regs = [&](int kk) {
    #pragma unroll
    for (int it = 0; it < CH; ++it) {
      int c = tid + it * 256;
      if (c < ACH) {
        int row = c >> 2, ch = (c & 3) * 8;
        int gm = bm + row;
        pr[it] = make_uint4(0u, 0u, 0u, 0u);
        if (gm < M) pr[it] = *(const uint4*)(A + (size_t)gm * K + kk + ch);
      } else {
        int c2 = c - ACH;
        int row = c2 >> 2, ch = (c2 & 3) * 8;
        pr[it] = *(const uint4*)(Bt + (size_t)(bn + row) * K + kk + ch);
      }
    }
  };

  load_regs(0);
  int buf = 0;
  for (int k0 = 0; k0 < K; k0 += 32, buf ^= 1) {
    #pragma unroll
    for (int it = 0; it < CH; ++it) {
      int c = tid + it * 256;
      if (c < ACH)
        *(uint4*)&As[buf][c >> 2][(c & 3) * 8] = pr[it];
      else {
        int c2 = c - ACH;
        *(uint4*)&Bs[buf][c2 >> 2][(c2 & 3) * 8] = pr[it];
      }
    }
    if (k0 + 32 < K) load_regs(k0 + 32);   // prefetch; flies across MFMA block
    __syncthreads();
    short8 af[NI], bfr[NJ];
    #pragma unroll
    for (int i = 0; i < NI; ++i)
      af[i] = *(const short8*)&As[buf][wm + i * 16 + l16][quad * 8];
    #pragma unroll
    for (int j = 0; j < NJ; ++j)
      bfr[j] = *(const short8*)&Bs[buf][wn + j * 16 + l16][quad * 8];
    #pragma unroll
    for (int i = 0; i < NI; ++i)
      #pragma unroll
      for (int j = 0; j < NJ; ++j)
        acc[i][j] = __builtin_amdgcn_mfma_f32_16x16x32_bf16(
            af[i], bfr[j], acc[i][j], 0, 0, 0);
    // no trailing barrier: next iter writes the other LDS buffer
  }

  if (EPI == 6) {
    const int sec = (bn + wn) >> 9;   // 0=q, 1=k, 2=v (wave-uniform; TN=128)
    #pragma unroll
    for (int i = 0; i < NI; ++i) {
      int gm0 = bm + wm + i * 16 + quad * 4;
      #pragma unroll
      for (int r = 0; r < 4; ++r) {
        int gm = gm0 + r;
        if (gm >= M) continue;
        size_t rowoff = (size_t)gm * N;
        if (sec < 2) {
          int ip = gm; if (ip >= 2046) ip -= 2046; if (ip >= 1023) ip -= 1023;
          float sc = (sec == 0) ? 0.125f : 1.f;
          #pragma unroll
          for (int j = 0; j < 2; ++j) {
            int gn = bn + wn + j * 16 + l16;
            float v0 = acc[i][j][r] + bias[gn];
            float v1 = acc[i][j + 2][r] + bias[gn + 32];
            float2 t = rtab[ip * 32 + j * 16 + l16];
            Cb[rowoff + gn]      = f2bf((v0 * t.x - v1 * t.y) * sc);
            Cb[rowoff + gn + 32] = f2bf((v1 * t.x + v0 * t.y) * sc);
          }
        } else {
          #pragma unroll
          for (int j = 0; j < 4; ++j) {
            int gn = bn + wn + j * 16 + l16;
            Cb[rowoff + gn] = f2bf(acc[i][j][r] + bias[gn]);
          }
        }
      }
    }
    return;
  }

  #pragma unroll
  for (int j = 0; j < NJ; ++j) {
    int gn = bn + wn + j * 16 + l16;
    float bv = bias[gn];
    #pragma unroll
    for (int i = 0; i < NI; ++i) {
      int gm0 = bm + wm + i * 16 + quad * 4;
      #pragma unroll
      for (int r = 0; r < 4; ++r) {
        int gm = gm0 + r;
        if (gm < M) {
          float v = acc[i][j][r] + bv;
          size_t off = (size_t)gm * N + gn;
          if (EPI == 1) {
            Cf[off] = v + res[off];
          } else if (EPI == 2) {
            Cb[off] = f2bf(0.5f * v * (1.f + erff(v * 0.70710678118f)));
          } else if (EPI == 3) {
            Cb[off] = f2bf(v);
          } else {
            Cf[off] = v;
            Cf2[off] = v;
          }
        }
      }
    }
  }
}

// ---------------------------------------------------------------------------
// MFMA flash attention, v3: split-K (NSPLIT=2) + XCD-aware swizzle.
//  Grid: 1024 blocks, 1-D. Decode so all 16 q-tiles sharing a
//  (head, batch, chunk) group land on the SAME XCD (bid % 8 == group % 8):
//  each XCD then touches one head's K/V (~2 MB) -> L2-resident.
//  - Q A-fragments: direct global->reg (no Qs LDS; LDS 27.6 KB -> 5 blk/CU).
//  - K fragments: direct global->reg prefetch (B-frag layout).
//  - V: conflict-free packed-b32 transpose staging, double-buffered,
//    ONE barrier per iter.
//  - Per-chunk online softmax with defer-max (THR=8), deferred l-reduction.
//  - Writes UNNORMALIZED fp32 partial O + (m, l) per row; attn_combine merges.
// ---------------------------------------------------------------------------
#define APITCH 72

__global__ __launch_bounds__(256) void attn_kernel(
    const unsigned short* __restrict__ qkvb,
    float* __restrict__ Opart, float2* __restrict__ ml) {
  // swizzled decode: bid = slot*8 + xcd; group g = ghi*8 + xcd
  const int bid = blockIdx.x;
  const int xcd = bid & 7, slot = bid >> 3;
  const int qt = slot & 15, ghi = slot >> 4;     // qt 0..15, ghi 0..7
  const int g = ghi * 8 + xcd;                   // 0..63
  const int h = g & 7;
  const int z = g >> 3;                          // 0..7
  const int b = z >> 1, c = z & 1;
  const int qt0 = qt * 64;
  const int j0base = c * KCHUNK;

  const int tid = threadIdx.x;
  const int lane = tid & 63, wave = tid >> 6;
  const int quad = lane >> 4, l16 = lane & 15;

  __shared__ __align__(16) unsigned short Vt[2][HD][APITCH];
  __shared__ __align__(16) unsigned short Ps[4][16][APITCH];

  // ---- Q A-fragments: direct global->reg ----
  short8 aq0 = {0, 0, 0, 0, 0, 0, 0, 0}, aq1 = aq0;
  {
    int qrow = qt0 + wave * 16 + l16;
    if (qrow < NPATCH) {
      const uint4* qr = (const uint4*)(qkvb + (size_t)(b * NPATCH + qrow) * (3 * DIM) + h * HD + quad * 8);
      aq0 = __builtin_bit_cast(short8, qr[0]);
      aq1 = __builtin_bit_cast(short8, qr[4]);   // +32 shorts
    }
  }

  // ---- V prefetch: thread covers keys {2kp, 2kp+1}, dims dg*8..dg*8+7 ----
  const int kp = tid & 31, dg = tid >> 5;
  uint4 pv0, pv1;
  auto load_v = [&](int j0) {
    pv0 = pv1 = make_uint4(0u, 0u, 0u, 0u);
    int j = j0 + 2 * kp;
    const unsigned short* vb = qkvb + (size_t)(b * NPATCH + j) * (3 * DIM) + 2 * DIM + h * HD + dg * 8;
    if (j < NPATCH)     pv0 = *(const uint4*)vb;
    if (j + 1 < NPATCH) pv1 = *(const uint4*)(vb + 3 * DIM);
  };

  // ---- K fragment prefetch: per-lane direct global (B-frag layout) ----
  const unsigned short* kbase = qkvb + (size_t)b * NPATCH * (3 * DIM) + DIM + (size_t)h * HD;
  uint4 nk0[4], nk1[4];
  auto load_k = [&](int j0) {
    #pragma unroll
    for (int j = 0; j < 4; ++j) {
      int row = j0 + j * 16 + l16;
      nk0[j] = make_uint4(0u, 0u, 0u, 0u);
      nk1[j] = nk0[j];
      if (row < NPATCH) {
        const uint4* kr = (const uint4*)(kbase + (size_t)row * (3 * DIM) + quad * 8);
        nk0[j] = kr[0];   // hd quad*8 .. +7
        nk1[j] = kr[4];   // hd 32+quad*8 .. +7
      }
    }
  };

  load_v(j0base);
  load_k(j0base);

  float4v accO[4];
  #pragma unroll
  for (int j2 = 0; j2 < 4; ++j2) accO[j2] = (float4v){0.f, 0.f, 0.f, 0.f};
  float m_run[4] = {-1e30f, -1e30f, -1e30f, -1e30f};
  float lp[4] = {0.f, 0.f, 0.f, 0.f};

  int buf = 0;
  for (int t = 0; t < KCHUNK / 64; ++t, buf ^= 1) {
    const int j0 = j0base + t * 64;
    // stage V -> Vt[buf] (conflict-free packed b32 writes)
    {
      unsigned short va[8], vb8[8];
      *(uint4*)&va[0] = pv0;
      *(uint4*)&vb8[0] = pv1;
      #pragma unroll
      for (int u = 0; u < 8; ++u) {
        unsigned pk = (unsigned)va[u] | ((unsigned)vb8[u] << 16);
        *(unsigned*)&Vt[buf][dg * 8 + u][2 * kp] = pk;
      }
    }
    __syncthreads();
    // no trailing barrier: next iter writes the other Vt buffer (race-free)

    // QK^T from prefetched K fragments
    float4v s[4];
    __builtin_amdgcn_s_setprio(1);
    #pragma unroll
    for (int j = 0; j < 4; ++j) {
      s[j] = (float4v){0.f, 0.f, 0.f, 0.f};
      s[j] = __builtin_amdgcn_mfma_f32_16x16x32_bf16(
          aq0, __builtin_bit_cast(short8, nk0[j]), s[j], 0, 0, 0);
      s[j] = __builtin_amdgcn_mfma_f32_16x16x32_bf16(
          aq1, __builtin_bit_cast(short8, nk1[j]), s[j], 0, 0, 0);
    }
    __builtin_amdgcn_s_setprio(0);

    // prefetch next K/V into regs; latency hides under softmax + PV
    if (t + 1 < KCHUNK / 64) { load_k(j0 + 64); load_v(j0 + 64); }

    // online softmax (per-chunk)
    float mx[4];
    #pragma unroll
    for (int r = 0; r < 4; ++r)
      mx[r] = fmaxf(fmaxf(s[0][r], s[1][r]), fmaxf(s[2][r], s[3][r]));
    #pragma unroll
    for (int mask = 1; mask < 16; mask <<= 1)
      #pragma unroll
      for (int r = 0; r < 4; ++r)
        mx[r] = fmaxf(mx[r], __shfl_xor(mx[r], mask));
    float gmax = fmaxf(fmaxf(mx[0] - m_run[0], mx[1] - m_run[1]),
                       fmaxf(mx[2] - m_run[2], mx[3] - m_run[3]));
    if (!__all(gmax <= 8.f)) {
      #pragma unroll
      for (int r = 0; r < 4; ++r) {
        float mnew = fmaxf(m_run[r], mx[r]);
        float al = __expf(m_run[r] - mnew);
        m_run[r] = mnew;
        lp[r] *= al;
        #pragma unroll
        for (int j2 = 0; j2 < 4; ++j2) accO[j2][r] *= al;
      }
    }
    #pragma unroll
    for (int j = 0; j < 4; ++j) {
      bool valid = (j0 + j * 16 + l16) < NPATCH;
      #pragma unroll
      for (int r = 0; r < 4; ++r) {
        float p = valid ? __expf(s[j][r] - m_run[r]) : 0.f;
        lp[r] += p;
        Ps[wave][quad * 4 + r][j * 16 + l16] = f2bf(p);
      }
    }

    // PV
    short8 pa0 = *(const short8*)&Ps[wave][l16][quad * 8];
    short8 pa1 = *(const short8*)&Ps[wave][l16][32 + quad * 8];
    __builtin_amdgcn_s_setprio(1);
    #pragma unroll
    for (int j2 = 0; j2 < 4; ++j2) {
      short8 v0 = *(const short8*)&Vt[buf][j2 * 16 + l16][quad * 8];
      short8 v1 = *(const short8*)&Vt[buf][j2 * 16 + l16][32 + quad * 8];
      accO[j2] = __builtin_amdgcn_mfma_f32_16x16x32_bf16(pa0, v0, accO[j2], 0, 0, 0);
      accO[j2] = __builtin_amdgcn_mfma_f32_16x16x32_bf16(pa1, v1, accO[j2], 0, 0, 0);
    }
    __builtin_amdgcn_s_setprio(0);
  }

  // deferred l reduction (over the 16 key-lanes)
  #pragma unroll
  for (int mask = 1; mask < 16; mask <<= 1)
    #pragma unroll
    for (int r = 0; r < 4; ++r)
      lp[r] += __shfl_xor(lp[r], mask);

  // write unnormalized fp32 partials + (m, l)
  const size_t cb = (((size_t)c * B_SZ + b) * NH + h) * NPATCH;
  #pragma unroll
  for (int r = 0; r < 4; ++r) {
    int qi = qt0 + wave * 16 + quad * 4 + r;
    if (qi < NPATCH) {
      size_t ro = (cb + qi) * HD + l16;
      #pragma unroll
      for (int j2 = 0; j2 < 4; ++j2)
        Opart[ro + j2 * 16] = accO[j2][r];
      if (l16 == 0) ml[cb + qi] = make_float2(m_run[r], lp[r]);
    }
  }
}

// ---------------------------------------------------------------------------
// Combine NSPLIT=2 partials: O = (w0*A0 + w1*A1) / (w0*l0 + w1*l1),
// w_c = exp(m_c - max(m)). One wave per row (64 dims). Output bf16 [row][DIM].
// ---------------------------------------------------------------------------
__global__ __launch_bounds__(256) void attn_combine(
    const float* __restrict__ Opart, const float2* __restrict__ ml,
    unsigned short* __restrict__ o) {
  int idx = blockIdx.x * 256 + threadIdx.x;
  if (idx >= B_SZ * NH * NPATCH * HD) return;
  int d = idx & 63;
  int rhi = idx >> 6;                    // (b*NH + h)*NPATCH + qi
  const size_t half = (size_t)B_SZ * NH * NPATCH;
  float2 m0 = ml[rhi], m1 = ml[half + rhi];
  float ms = fmaxf(m0.x, m1.x);
  float w0 = __expf(m0.x - ms), w1 = __expf(m1.x - ms);
  float lst = w0 * m0.y + w1 * m1.y;
  float a0 = Opart[(size_t)rhi * HD + d];
  float a1 = Opart[half * HD + (size_t)rhi * HD + d];
  float val = (w0 * a0 + w1 * a1) / lst;
  int qi = rhi % NPATCH;
  int bh = rhi / NPATCH;
  int hh = bh & 7, bb = bh >> 3;
  o[((size_t)bb * NPATCH + qi) * DIM + hh * HD + d] = f2bf(val);
}

// ---------------------------------------------------------------------------
extern "C" void kernel_launch(void* const* d_in, const int* in_sizes, int n_in,
                              void* d_out, int out_size, void* d_ws, size_t ws_size,
                              hipStream_t stream) {
  const float* x      = (const float*)d_in[0];
  const float* W_emb  = (const float*)d_in[1];
  const float* b_emb  = (const float*)d_in[2];
  const float* ln1_g  = (const float*)d_in[3];
  const float* ln1_b  = (const float*)d_in[4];
  const float* W_qkv  = (const float*)d_in[5];
  const float* b_qkv  = (const float*)d_in[6];
  const float* W_proj = (const float*)d_in[7];
  const float* b_proj = (const float*)d_in[8];
  const float* ln2_g  = (const float*)d_in[9];
  const float* ln2_b  = (const float*)d_in[10];
  const float* W_mlp1 = (const float*)d_in[11];
  const float* b_mlp1 = (const float*)d_in[12];
  const float* W_mlp2 = (const float*)d_in[13];
  const float* b_mlp2 = (const float*)d_in[14];
  const float* lnf_g  = (const float*)d_in[15];
  const float* lnf_b  = (const float*)d_in[16];
  float* out = (float*)d_out;

  float* h              = (float*)d_ws;
  unsigned short* qkvb  = (unsigned short*)(h + (size_t)M_ROWS * DIM);
  unsigned short* midbf = qkvb;   // alias: qkvb dead after attn
  unsigned short* ybf   = qkvb + (size_t)M_ROWS * MLP_HID;
  unsigned short* obf   = ybf;    // alias: ybf dead after its GEMM
  unsigned short* wqkv_t  = ybf + (size_t)M_ROWS * DIM;
  unsigned short* wproj_t = wqkv_t  + (size_t)NLAYERS * DIM * 3 * DIM;
  unsigned short* wmlp1_t = wproj_t + (size_t)NLAYERS * DIM * DIM;
  unsigned short* wmlp2_t = wmlp1_t + (size_t)NLAYERS * DIM * MLP_HID;
  float2* rtab = (float2*)(wmlp2_t + (size_t)NLAYERS * MLP_HID * DIM);
  unsigned short* Pm    = (unsigned short*)(rtab + (size_t)NPATCH * 32);
  unsigned short* Wembt = Pm + (size_t)M_ROWS * KEMB;
  float* Opart          = (float*)(Wembt + (size_t)DIM * KEMB);
  float2* mlbuf         = (float2*)(Opart + (size_t)NSPLIT * B_SZ * NH * NPATCH * HD);

  wcvt_kernel<<<dim3(3 * DIM / 32, DIM / 32, NLAYERS), 256, 0, stream>>>(W_qkv,  wqkv_t,  DIM, 3 * DIM);
  wcvt_kernel<<<dim3(DIM / 32, DIM / 32, NLAYERS),     256, 0, stream>>>(W_proj, wproj_t, DIM, DIM);
  wcvt_kernel<<<dim3(MLP_HID / 32, DIM / 32, NLAYERS), 256, 0, stream>>>(W_mlp1, wmlp1_t, DIM, MLP_HID);
  wcvt_kernel<<<dim3(DIM / 32, MLP_HID / 32, NLAYERS), 256, 0, stream>>>(W_mlp2, wmlp2_t, MLP_HID, DIM);
  rope_tab_kernel<<<(NPATCH * 32 + 255) / 256, 256, 0, stream>>>(rtab);
  patch_kernel<<<(M_ROWS * KEMB + 255) / 256, 256, 0, stream>>>(x, Pm);
  wemb_cvt_kernel<<<(DIM * KEMB + 255) / 256, 256, 0, stream>>>(W_emb, Wembt);

  const int MT64 = (M_ROWS + 63) / 64;   // 64
  const int LNG = (M_ROWS + 3) / 4;      // 1023
  const int CMB = (B_SZ * NH * NPATCH * HD + 255) / 256;

  // embed: out & h = Pm @ Wembt^T + b_emb  (TN=64: 512 blocks)
  mfma_gemm<64, 64, 5><<<dim3(DIM / 64, MT64), 256, 0, stream>>>(
      Pm, Wembt, b_emb, nullptr, out, h, nullptr, nullptr, M_ROWS, DIM, KEMB);

  for (int L = 0; L < NLAYERS; ++L) {
    ln_kernel<true><<<LNG, 256, 0, stream>>>(h, ln1_g + L * DIM, ln1_b + L * DIM, ybf, M_ROWS);
    // qkv with fused RoPE (TN=128: 768 blocks)
    mfma_gemm<64, 128, 6><<<dim3(3 * DIM / 128, MT64), 256, 0, stream>>>(
        ybf, wqkv_t + (size_t)L * DIM * 3 * DIM, b_qkv + L * 3 * DIM,
        nullptr, nullptr, nullptr, qkvb, rtab, M_ROWS, 3 * DIM, DIM);
    attn_kernel<<<dim3(16 * 8 * B_SZ * NSPLIT), 256, 0, stream>>>(qkvb, Opart, mlbuf);
    attn_combine<<<CMB, 256, 0, stream>>>(Opart, mlbuf, obf);
    // proj: h += o @ Wp + bias  (TN=64: 512 blocks)
    mfma_gemm<64, 64, 1><<<dim3(DIM / 64, MT64), 256, 0, stream>>>(
        obf, wproj_t + (size_t)L * DIM * DIM, b_proj + L * DIM,
        h, h, nullptr, nullptr, nullptr, M_ROWS, DIM, DIM);
    ln_kernel<true><<<LNG, 256, 0, stream>>>(h, ln2_g + L * DIM, ln2_b + L * DIM, ybf, M_ROWS);
    // mlp1 (TN=128: 1024 blocks)
    mfma_gemm<64, 128, 2><<<dim3(MLP_HID / 128, MT64), 256, 0, stream>>>(
        ybf, wmlp1_t + (size_t)L * DIM * MLP_HID, b_mlp1 + L * MLP_HID,
        nullptr, nullptr, nullptr, midbf, nullptr, M_ROWS, MLP_HID, DIM);
    // mlp2: h += mid @ Wm2 + bias  (TN=64: 512 blocks)
    mfma_gemm<64, 64, 1><<<dim3(DIM / 64, MT64), 256, 0, stream>>>(
        midbf, wmlp2_t + (size_t)L * MLP_HID * DIM, b_mlp2 + L * DIM,
        h, h, nullptr, nullptr, nullptr, M_ROWS, DIM, MLP_HID);
  }

  ln_kernel<false><<<LNG, 256, 0, stream>>>(h, lnf_g, lnf_b, out + (size_t)M_ROWS * DIM, M_ROWS);
}

// Round 3
// 692.919 us; speedup vs baseline: 1.1041x; 1.1041x over previous
//
#include <hip/hip_runtime.h>
#include <hip/hip_bf16.h>
#include <math.h>

#define B_SZ 4
#define T_LEN 8192
#define C_IN 7
#define NPATCH 1023
#define DIM 512
#define NH 8
#define HD 64
#define NLAYERS 4
#define MLP_HID 2048
#define M_ROWS (B_SZ * NPATCH)   // 4092
#define KEMB 128                 // padded patch length (112 real + 16 zero)
#define LN_EPS 1e-5f

typedef __attribute__((ext_vector_type(8))) short short8;
typedef __attribute__((ext_vector_type(4))) float float4v;

static __device__ __forceinline__ unsigned short f2bf(float f) {
  __hip_bfloat16 h = __float2bfloat16(f);
  return *reinterpret_cast<unsigned short*>(&h);
}
static __device__ __forceinline__ float bf2f(unsigned short u) {
  return __uint_as_float(((unsigned)u) << 16);
}

// ---------------------------------------------------------------------------
// Patch gather: Pm[row][c*16+p] = bf16(x[b, i*8+p, c]); cols 112..127 = 0.
// ---------------------------------------------------------------------------
__global__ __launch_bounds__(256) void patch_kernel(
    const float* __restrict__ x, unsigned short* __restrict__ Pm) {
  int idx = blockIdx.x * 256 + threadIdx.x;
  if (idx >= M_ROWS * KEMB) return;
  int row = idx >> 7, c = idx & 127;
  float v = 0.f;
  if (c < 112) {
    int b = row / NPATCH, i = row - b * NPATCH;
    int ci = c >> 4, p = c & 15;
    v = x[((size_t)b * T_LEN + (size_t)i * 8 + p) * C_IN + ci];
  }
  Pm[idx] = f2bf(v);
}

// ---------------------------------------------------------------------------
// W_emb convert: Wt[n][k] = bf16(W_emb[k][n]) for k<112, 0 for k in [112,128).
// ---------------------------------------------------------------------------
__global__ __launch_bounds__(256) void wemb_cvt_kernel(
    const float* __restrict__ W, unsigned short* __restrict__ Wt) {
  int idx = blockIdx.x * 256 + threadIdx.x;
  if (idx >= DIM * KEMB) return;
  int n = idx >> 7, k = idx & 127;
  float v = (k < 112) ? W[(size_t)k * DIM + n] : 0.f;
  Wt[idx] = f2bf(v);
}

// ---------------------------------------------------------------------------
// LayerNorm, 4 rows/block. BF: bf16 vs fp32 out.
// ---------------------------------------------------------------------------
template <bool BF>
__global__ __launch_bounds__(256) void ln_kernel(
    const float* __restrict__ in, const float* __restrict__ g,
    const float* __restrict__ bb, void* __restrict__ outv, int M) {
  int row = blockIdx.x * 4 + (threadIdx.x >> 6);
  if (row >= M) return;
  int lane = threadIdx.x & 63;
  const float* xr = in + (size_t)row * DIM;
  float v[8];
  float s = 0.f;
  #pragma unroll
  for (int k = 0; k < 8; ++k) { v[k] = xr[lane + 64 * k]; s += v[k]; }
  #pragma unroll
  for (int off = 32; off; off >>= 1) s += __shfl_down(s, off);
  s = __shfl(s, 0);
  float mu = s * (1.f / DIM);
  float q = 0.f;
  #pragma unroll
  for (int k = 0; k < 8; ++k) { float d = v[k] - mu; q = fmaf(d, d, q); }
  #pragma unroll
  for (int off = 32; off; off >>= 1) q += __shfl_down(q, off);
  q = __shfl(q, 0);
  float rstd = rsqrtf(q * (1.f / DIM) + LN_EPS);
  #pragma unroll
  for (int k = 0; k < 8; ++k) {
    int d = lane + 64 * k;
    float r = (v[k] - mu) * rstd * g[d] + bb[d];
    if (BF)
      ((unsigned short*)outv)[(size_t)row * DIM + d] = f2bf(r);
    else
      ((float*)outv)[(size_t)row * DIM + d] = r;
  }
}

// ---------------------------------------------------------------------------
// Weight convert + transpose: W[K][N] fp32 -> Wt[N][K] bf16 (per layer z).
// ---------------------------------------------------------------------------
__global__ __launch_bounds__(256) void wcvt_kernel(
    const float* __restrict__ W, unsigned short* __restrict__ Wt, int K, int N) {
  __shared__ float tile[32][33];
  int n0 = blockIdx.x * 32, k0 = blockIdx.y * 32, L = blockIdx.z;
  const float* Ws = W + (size_t)L * K * N;
  unsigned short* Wd = Wt + (size_t)L * K * N;
  int tx = threadIdx.x & 31, ty = threadIdx.x >> 5;
  #pragma unroll
  for (int i = 0; i < 4; ++i)
    tile[ty + i * 8][tx] = Ws[(size_t)(k0 + ty + i * 8) * N + n0 + tx];
  __syncthreads();
  #pragma unroll
  for (int i = 0; i < 4; ++i)
    Wd[(size_t)(n0 + ty + i * 8) * K + k0 + tx] = f2bf(tile[tx][ty + i * 8]);
}

// ---------------------------------------------------------------------------
// RoPE cos/sin table: tab[i*32+j] = (cos, sin) of i * 10000^(-j/32).
// ---------------------------------------------------------------------------
__global__ __launch_bounds__(256) void rope_tab_kernel(float2* __restrict__ tab) {
  int idx = blockIdx.x * 256 + threadIdx.x;
  if (idx >= NPATCH * 32) return;
  int i = idx >> 5, j = idx & 31;
  float inv = powf(10000.0f, -(float)j * (1.0f / 32.0f));
  float sn, cs;
  sincosf((float)i * inv, &sn, &cs);
  tab[idx] = make_float2(cs, sn);
}

// ---------------------------------------------------------------------------
// bf16 MFMA GEMM, TM x TN tile, BK=32, 4 waves (2x2), double-buffered LDS,
// ONE barrier per K-iter: write LDS[buf] -> prefetch next tile to regs ->
// __syncthreads -> MFMA from LDS[buf]. No trailing barrier (next iter writes
// the other buffer; race-free). Prefetch loads fly across the MFMA block.
// TM=TN=128: 4x4 fragments/wave, 16 MFMA : 8 ds_read_b128 per iter (m93 step).
// EPI: 1 = bias + res -> fp32 (res==Cf ok: h += ...);
//      2 = bias + GELU -> bf16; 3 = bias -> bf16;
//      5 = bias -> fp32 to BOTH Cf and Cf2 (embed);
//      6 = bias + RoPE (q scaled 1/8) -> bf16 (qkv; needs WN=64).
// ---------------------------------------------------------------------------
template <int TM, int TN, int EPI>
__global__ __launch_bounds__(256) void mfma_gemm(
    const unsigned short* __restrict__ A, const unsigned short* __restrict__ Bt,
    const float* __restrict__ bias, const float* __restrict__ res,
    float* __restrict__ Cf, float* __restrict__ Cf2,
    unsigned short* __restrict__ Cb, const float2* __restrict__ rtab,
    int M, int N, int K) {
  constexpr int WM = TM / 2, WN = TN / 2;
  constexpr int NI = WM / 16, NJ = WN / 16;
  constexpr int ACH = TM * 4;               // A uint4 chunks per K-tile
  constexpr int TCH = (TM + TN) * 4;        // total chunks
  constexpr int CH = TCH / 256;             // chunks per thread
  __shared__ __align__(16) unsigned short As[2][TM][40];
  __shared__ __align__(16) unsigned short Bs[2][TN][40];
  const int bm = blockIdx.y * TM;
  const int bn = blockIdx.x * TN;
  const int tid = threadIdx.x;
  const int lane = tid & 63, wave = tid >> 6;
  const int quad = lane >> 4, l16 = lane & 15;
  const int wm = (wave & 1) * WM;
  const int wn = (wave >> 1) * WN;

  float4v acc[NI][NJ];
  #pragma unroll
  for (int i = 0; i < NI; ++i)
    #pragma unroll
    for (int j = 0; j < NJ; ++j)
      acc[i][j] = (float4v){0.f, 0.f, 0.f, 0.f};

  uint4 pr[CH];
  auto load_regs = [&](int kk) {
    #pragma unroll
    for (int it = 0; it < CH; ++it) {
      int c = tid + it * 256;
      if (c < ACH) {
        int row = c >> 2, ch = (c & 3) * 8;
        int gm = bm + row;
        pr[it] = make_uint4(0u, 0u, 0u, 0u);
        if (gm < M) pr[it] = *(const uint4*)(A + (size_t)gm * K + kk + ch);
      } else {
        int c2 = c - ACH;
        int row = c2 >> 2, ch = (c2 & 3) * 8;
        pr[it] = *(const uint4*)(Bt + (size_t)(bn + row) * K + kk + ch);
      }
    }
  };

  load_regs(0);
  int buf = 0;
  for (int k0 = 0; k0 < K; k0 += 32, buf ^= 1) {
    #pragma unroll
    for (int it = 0; it < CH; ++it) {
      int c = tid + it * 256;
      if (c < ACH)
        *(uint4*)&As[buf][c >> 2][(c & 3) * 8] = pr[it];
      else {
        int c2 = c - ACH;
        *(uint4*)&Bs[buf][c2 >> 2][(c2 & 3) * 8] = pr[it];
      }
    }
    if (k0 + 32 < K) load_regs(k0 + 32);   // prefetch; flies across MFMA block
    __syncthreads();
    short8 af[NI], bfr[NJ];
    #pragma unroll
    for (int i = 0; i < NI; ++i)
      af[i] = *(const short8*)&As[buf][wm + i * 16 + l16][quad * 8];
    #pragma unroll
    for (int j = 0; j < NJ; ++j)
      bfr[j] = *(const short8*)&Bs[buf][wn + j * 16 + l16][quad * 8];
    __builtin_amdgcn_s_setprio(1);
    #pragma unroll
    for (int i = 0; i < NI; ++i)
      #pragma unroll
      for (int j = 0; j < NJ; ++j)
        acc[i][j] = __builtin_amdgcn_mfma_f32_16x16x32_bf16(
            af[i], bfr[j], acc[i][j], 0, 0, 0);
    __builtin_amdgcn_s_setprio(0);
    // no trailing barrier: next iter writes the other LDS buffer
  }

  if (EPI == 6) {
    const int sec = (bn + wn) >> 9;   // 0=q, 1=k, 2=v (wave-uniform; WN=64)
    #pragma unroll
    for (int i = 0; i < NI; ++i) {
      int gm0 = bm + wm + i * 16 + quad * 4;
      #pragma unroll
      for (int r = 0; r < 4; ++r) {
        int gm = gm0 + r;
        if (gm >= M) continue;
        size_t rowoff = (size_t)gm * N;
        if (sec < 2) {
          int ip = gm; if (ip >= 2046) ip -= 2046; if (ip >= 1023) ip -= 1023;
          float sc = (sec == 0) ? 0.125f : 1.f;
          #pragma unroll
          for (int j = 0; j < NJ / 2; ++j) {
            int gn = bn + wn + j * 16 + l16;
            float v0 = acc[i][j][r] + bias[gn];
            float v1 = acc[i][j + NJ / 2][r] + bias[gn + 32];
            float2 t = rtab[ip * 32 + j * 16 + l16];
            Cb[rowoff + gn]      = f2bf((v0 * t.x - v1 * t.y) * sc);
            Cb[rowoff + gn + 32] = f2bf((v1 * t.x + v0 * t.y) * sc);
          }
        } else {
          #pragma unroll
          for (int j = 0; j < NJ; ++j) {
            int gn = bn + wn + j * 16 + l16;
            Cb[rowoff + gn] = f2bf(acc[i][j][r] + bias[gn]);
          }
        }
      }
    }
    return;
  }

  #pragma unroll
  for (int j = 0; j < NJ; ++j) {
    int gn = bn + wn + j * 16 + l16;
    float bv = bias[gn];
    #pragma unroll
    for (int i = 0; i < NI; ++i) {
      int gm0 = bm + wm + i * 16 + quad * 4;
      #pragma unroll
      for (int r = 0; r < 4; ++r) {
        int gm = gm0 + r;
        if (gm < M) {
          float v = acc[i][j][r] + bv;
          size_t off = (size_t)gm * N + gn;
          if (EPI == 1) {
            Cf[off] = v + res[off];
          } else if (EPI == 2) {
            Cb[off] = f2bf(0.5f * v * (1.f + erff(v * 0.70710678118f)));
          } else if (EPI == 3) {
            Cb[off] = f2bf(v);
          } else {
            Cf[off] = v;
            Cf2[off] = v;
          }
        }
      }
    }
  }
}

// ---------------------------------------------------------------------------
// MFMA flash attention v4 = R0 skeleton (best measured: coalesced block-wide
// K->LDS staging) + proven add-ons:
//  - double-buffered Ks/Vt -> ONE barrier per iter (R1/R2 scheme)
//  - conflict-free packed-b32 V transpose (R1)
//  - defer-max (THR=8) + deferred l-reduction (R1)
//  - s_setprio(1) around MFMA clusters
//  - XCD swizzle (R2: FETCH 34.8->6.2 MB): 1-D grid, blocks sharing (b,h)
//    land on the same XCD -> K/V L2-resident.
// No split-K (R2 showed per-block overhead duplication outweighs parallelism).
// ---------------------------------------------------------------------------
#define APITCH 72

__global__ __launch_bounds__(256) void attn_kernel(
    const unsigned short* __restrict__ qkvb, unsigned short* __restrict__ o) {
  // XCD-aware decode: bid = slot*8 + xcd; (b,h) group = xcd + 8*(slot>>4)
  const int bid = blockIdx.x;
  const int xcd = bid & 7, slot = bid >> 3;
  const int qt0 = (slot & 15) * 64;
  const int gh = xcd + 8 * (slot >> 4);    // 0..31
  const int h = gh & 7, b = gh >> 3;

  const int tid = threadIdx.x;
  const int lane = tid & 63, wave = tid >> 6;
  const int quad = lane >> 4, l16 = lane & 15;

  __shared__ __align__(16) unsigned short Qs[64][APITCH];
  __shared__ __align__(16) unsigned short Ks[2][64][APITCH];
  __shared__ __align__(16) unsigned short Vt[2][HD][APITCH];
  __shared__ __align__(16) unsigned short Ps[4][16][APITCH];

  const int sr = tid >> 2;
  const int sc0 = (tid & 3) * 16;

  // ---- Q stage (one-time, coalesced) ----
  {
    int qi = qt0 + sr;
    uint4 a = make_uint4(0u, 0u, 0u, 0u), b2 = a;
    if (qi < NPATCH) {
      const uint4* src = (const uint4*)(qkvb + (size_t)(b * NPATCH + qi) * (3 * DIM) + h * HD + sc0);
      a = src[0]; b2 = src[1];
    }
    *(uint4*)&Qs[sr][sc0] = a;
    *(uint4*)&Qs[sr][sc0 + 8] = b2;
  }

  // ---- K prefetch: coalesced, row sr, 32B/thread ----
  uint4 pk0, pk1;
  auto load_k = [&](int j0) {
    pk0 = pk1 = make_uint4(0u, 0u, 0u, 0u);
    int j = j0 + sr;
    if (j < NPATCH) {
      const unsigned short* kb = qkvb + (size_t)(b * NPATCH + j) * (3 * DIM) + DIM + h * HD;
      pk0 = *(const uint4*)(kb + sc0);
      pk1 = *(const uint4*)(kb + sc0 + 8);
    }
  };

  // ---- V prefetch: thread covers keys {2kp, 2kp+1}, dims dg*8..dg*8+7 ----
  const int kp = tid & 31, dg = tid >> 5;
  uint4 pv0, pv1;
  auto load_v = [&](int j0) {
    pv0 = pv1 = make_uint4(0u, 0u, 0u, 0u);
    int j = j0 + 2 * kp;
    const unsigned short* vb = qkvb + (size_t)(b * NPATCH + j) * (3 * DIM) + 2 * DIM + h * HD + dg * 8;
    if (j < NPATCH)     pv0 = *(const uint4*)vb;
    if (j + 1 < NPATCH) pv1 = *(const uint4*)(vb + 3 * DIM);
  };

  load_k(0);
  load_v(0);
  __syncthreads();   // Qs visible

  short8 aq0 = *(const short8*)&Qs[wave * 16 + l16][quad * 8];
  short8 aq1 = *(const short8*)&Qs[wave * 16 + l16][32 + quad * 8];

  float4v accO[4];
  #pragma unroll
  for (int j2 = 0; j2 < 4; ++j2) accO[j2] = (float4v){0.f, 0.f, 0.f, 0.f};
  float m_run[4] = {-1e30f, -1e30f, -1e30f, -1e30f};
  float lp[4] = {0.f, 0.f, 0.f, 0.f};

  int buf = 0;
  for (int j0 = 0; j0 < NPATCH; j0 += 64, buf ^= 1) {
    // stage K (coalesced b128) and V (conflict-free packed b32) -> [buf]
    {
      *(uint4*)&Ks[buf][sr][sc0] = pk0;
      *(uint4*)&Ks[buf][sr][sc0 + 8] = pk1;
      unsigned short va[8], vb8[8];
      *(uint4*)&va[0] = pv0;
      *(uint4*)&vb8[0] = pv1;
      #pragma unroll
      for (int u = 0; u < 8; ++u) {
        unsigned pk = (unsigned)va[u] | ((unsigned)vb8[u] << 16);
        *(unsigned*)&Vt[buf][dg * 8 + u][2 * kp] = pk;
      }
    }
    __syncthreads();
    // no trailing barrier: next iter writes the other buffer (race-free)

    // prefetch next K/V tile into regs; flies over compute
    if (j0 + 64 < NPATCH) { load_k(j0 + 64); load_v(j0 + 64); }

    // QK^T from LDS K (2-way bank alias only — free)
    float4v s[4];
    __builtin_amdgcn_s_setprio(1);
    #pragma unroll
    for (int j = 0; j < 4; ++j) {
      s[j] = (float4v){0.f, 0.f, 0.f, 0.f};
      short8 bk0 = *(const short8*)&Ks[buf][j * 16 + l16][quad * 8];
      short8 bk1 = *(const short8*)&Ks[buf][j * 16 + l16][32 + quad * 8];
      s[j] = __builtin_amdgcn_mfma_f32_16x16x32_bf16(aq0, bk0, s[j], 0, 0, 0);
      s[j] = __builtin_amdgcn_mfma_f32_16x16x32_bf16(aq1, bk1, s[j], 0, 0, 0);
    }
    __builtin_amdgcn_s_setprio(0);

    // online softmax with defer-max; deferred l (per-lane partials)
    float mx[4];
    #pragma unroll
    for (int r = 0; r < 4; ++r)
      mx[r] = fmaxf(fmaxf(s[0][r], s[1][r]), fmaxf(s[2][r], s[3][r]));
    #pragma unroll
    for (int mask = 1; mask < 16; mask <<= 1)
      #pragma unroll
      for (int r = 0; r < 4; ++r)
        mx[r] = fmaxf(mx[r], __shfl_xor(mx[r], mask));
    float gmax = fmaxf(fmaxf(mx[0] - m_run[0], mx[1] - m_run[1]),
                       fmaxf(mx[2] - m_run[2], mx[3] - m_run[3]));
    if (!__all(gmax <= 8.f)) {
      #pragma unroll
      for (int r = 0; r < 4; ++r) {
        float mnew = fmaxf(m_run[r], mx[r]);
        float al = __expf(m_run[r] - mnew);
        m_run[r] = mnew;
        lp[r] *= al;
        #pragma unroll
        for (int j2 = 0; j2 < 4; ++j2) accO[j2][r] *= al;
      }
    }
    #pragma unroll
    for (int j = 0; j < 4; ++j) {
      bool valid = (j0 + j * 16 + l16) < NPATCH;
      #pragma unroll
      for (int r = 0; r < 4; ++r) {
        float p = valid ? __expf(s[j][r] - m_run[r]) : 0.f;
        lp[r] += p;
        Ps[wave][quad * 4 + r][j * 16 + l16] = f2bf(p);
      }
    }

    // PV (Ps is per-wave private: no barrier needed)
    short8 pa0 = *(const short8*)&Ps[wave][l16][quad * 8];
    short8 pa1 = *(const short8*)&Ps[wave][l16][32 + quad * 8];
    __builtin_amdgcn_s_setprio(1);
    #pragma unroll
    for (int j2 = 0; j2 < 4; ++j2) {
      short8 v0 = *(const short8*)&Vt[buf][j2 * 16 + l16][quad * 8];
      short8 v1 = *(const short8*)&Vt[buf][j2 * 16 + l16][32 + quad * 8];
      accO[j2] = __builtin_amdgcn_mfma_f32_16x16x32_bf16(pa0, v0, accO[j2], 0, 0, 0);
      accO[j2] = __builtin_amdgcn_mfma_f32_16x16x32_bf16(pa1, v1, accO[j2], 0, 0, 0);
    }
    __builtin_amdgcn_s_setprio(0);
  }

  // deferred l reduction (over the 16 key-lanes)
  #pragma unroll
  for (int mask = 1; mask < 16; mask <<= 1)
    #pragma unroll
    for (int r = 0; r < 4; ++r)
      lp[r] += __shfl_xor(lp[r], mask);

  #pragma unroll
  for (int r = 0; r < 4; ++r) {
    int qi = qt0 + wave * 16 + quad * 4 + r;
    if (qi < NPATCH) {
      float inv = 1.f / lp[r];
      size_t off = (size_t)(b * NPATCH + qi) * DIM + h * HD + l16;
      #pragma unroll
      for (int j2 = 0; j2 < 4; ++j2)
        o[off + j2 * 16] = f2bf(accO[j2][r] * inv);
    }
  }
}

// ---------------------------------------------------------------------------
extern "C" void kernel_launch(void* const* d_in, const int* in_sizes, int n_in,
                              void* d_out, int out_size, void* d_ws, size_t ws_size,
                              hipStream_t stream) {
  const float* x      = (const float*)d_in[0];
  const float* W_emb  = (const float*)d_in[1];
  const float* b_emb  = (const float*)d_in[2];
  const float* ln1_g  = (const float*)d_in[3];
  const float* ln1_b  = (const float*)d_in[4];
  const float* W_qkv  = (const float*)d_in[5];
  const float* b_qkv  = (const float*)d_in[6];
  const float* W_proj = (const float*)d_in[7];
  const float* b_proj = (const float*)d_in[8];
  const float* ln2_g  = (const float*)d_in[9];
  const float* ln2_b  = (const float*)d_in[10];
  const float* W_mlp1 = (const float*)d_in[11];
  const float* b_mlp1 = (const float*)d_in[12];
  const float* W_mlp2 = (const float*)d_in[13];
  const float* b_mlp2 = (const float*)d_in[14];
  const float* lnf_g  = (const float*)d_in[15];
  const float* lnf_b  = (const float*)d_in[16];
  float* out = (float*)d_out;

  float* h              = (float*)d_ws;
  unsigned short* qkvb  = (unsigned short*)(h + (size_t)M_ROWS * DIM);
  unsigned short* midbf = qkvb;   // alias: qkvb dead after attn
  unsigned short* ybf   = qkvb + (size_t)M_ROWS * MLP_HID;
  unsigned short* obf   = ybf;    // alias: ybf dead after its GEMM
  unsigned short* wqkv_t  = ybf + (size_t)M_ROWS * DIM;
  unsigned short* wproj_t = wqkv_t  + (size_t)NLAYERS * DIM * 3 * DIM;
  unsigned short* wmlp1_t = wproj_t + (size_t)NLAYERS * DIM * DIM;
  unsigned short* wmlp2_t = wmlp1_t + (size_t)NLAYERS * DIM * MLP_HID;
  float2* rtab = (float2*)(wmlp2_t + (size_t)NLAYERS * MLP_HID * DIM);
  unsigned short* Pm    = (unsigned short*)(rtab + (size_t)NPATCH * 32);
  unsigned short* Wembt = Pm + (size_t)M_ROWS * KEMB;

  wcvt_kernel<<<dim3(3 * DIM / 32, DIM / 32, NLAYERS), 256, 0, stream>>>(W_qkv,  wqkv_t,  DIM, 3 * DIM);
  wcvt_kernel<<<dim3(DIM / 32, DIM / 32, NLAYERS),     256, 0, stream>>>(W_proj, wproj_t, DIM, DIM);
  wcvt_kernel<<<dim3(MLP_HID / 32, DIM / 32, NLAYERS), 256, 0, stream>>>(W_mlp1, wmlp1_t, DIM, MLP_HID);
  wcvt_kernel<<<dim3(DIM / 32, MLP_HID / 32, NLAYERS), 256, 0, stream>>>(W_mlp2, wmlp2_t, MLP_HID, DIM);
  rope_tab_kernel<<<(NPATCH * 32 + 255) / 256, 256, 0, stream>>>(rtab);
  patch_kernel<<<(M_ROWS * KEMB + 255) / 256, 256, 0, stream>>>(x, Pm);
  wemb_cvt_kernel<<<(DIM * KEMB + 255) / 256, 256, 0, stream>>>(W_emb, Wembt);

  const int MT64 = (M_ROWS + 63) / 64;     // 64
  const int MT128 = (M_ROWS + 127) / 128;  // 32
  const int LNG = (M_ROWS + 3) / 4;        // 1023

  // embed: out & h = Pm @ Wembt^T + b_emb  (TN=64: 512 blocks)
  mfma_gemm<64, 64, 5><<<dim3(DIM / 64, MT64), 256, 0, stream>>>(
      Pm, Wembt, b_emb, nullptr, out, h, nullptr, nullptr, M_ROWS, DIM, KEMB);

  for (int L = 0; L < NLAYERS; ++L) {
    ln_kernel<true><<<LNG, 256, 0, stream>>>(h, ln1_g + L * DIM, ln1_b + L * DIM, ybf, M_ROWS);
    // qkv with fused RoPE (128x128 tiles: 12x32 = 384 blocks)
    mfma_gemm<128, 128, 6><<<dim3(3 * DIM / 128, MT128), 256, 0, stream>>>(
        ybf, wqkv_t + (size_t)L * DIM * 3 * DIM, b_qkv + L * 3 * DIM,
        nullptr, nullptr, nullptr, qkvb, rtab, M_ROWS, 3 * DIM, DIM);
    attn_kernel<<<dim3(512), 256, 0, stream>>>(qkvb, obf);
    // proj: h += o @ Wp + bias  (64x64: 512 blocks)
    mfma_gemm<64, 64, 1><<<dim3(DIM / 64, MT64), 256, 0, stream>>>(
        obf, wproj_t + (size_t)L * DIM * DIM, b_proj + L * DIM,
        h, h, nullptr, nullptr, nullptr, M_ROWS, DIM, DIM);
    ln_kernel<true><<<LNG, 256, 0, stream>>>(h, ln2_g + L * DIM, ln2_b + L * DIM, ybf, M_ROWS);
    // mlp1 + GELU (128x128 tiles: 16x32 = 512 blocks)
    mfma_gemm<128, 128, 2><<<dim3(MLP_HID / 128, MT128), 256, 0, stream>>>(
        ybf, wmlp1_t + (size_t)L * DIM * MLP_HID, b_mlp1 + L * MLP_HID,
        nullptr, nullptr, nullptr, midbf, nullptr, M_ROWS, MLP_HID, DIM);
    // mlp2: h += mid @ Wm2 + bias  (64x64: 512 blocks)
    mfma_gemm<64, 64, 1><<<dim3(DIM / 64, MT64), 256, 0, stream>>>(
        midbf, wmlp2_t + (size_t)L * MLP_HID * DIM, b_mlp2 + L * DIM,
        h, h, nullptr, nullptr, nullptr, M_ROWS, DIM, MLP_HID);
  }

  ln_kernel<false><<<LNG, 256, 0, stream>>>(h, lnf_g, lnf_b, out + (size_t)M_ROWS * DIM, M_ROWS);
}

// Round 4
// 683.856 us; speedup vs baseline: 1.1187x; 1.0133x over previous
//
#include <hip/hip_runtime.h>
#include <hip/hip_bf16.h>
#include <math.h>

#define B_SZ 4
#define T_LEN 8192
#define C_IN 7
#define NPATCH 1023
#define DIM 512
#define NH 8
#define HD 64
#define NLAYERS 4
#define MLP_HID 2048
#define M_ROWS (B_SZ * NPATCH)   // 4092
#define KEMB 128                 // padded patch length (112 real + 16 zero)
#define LN_EPS 1e-5f

typedef __attribute__((ext_vector_type(8))) short short8;
typedef __attribute__((ext_vector_type(4))) float float4v;

static __device__ __forceinline__ unsigned short f2bf(float f) {
  __hip_bfloat16 h = __float2bfloat16(f);
  return *reinterpret_cast<unsigned short*>(&h);
}
static __device__ __forceinline__ float bf2f(unsigned short u) {
  return __uint_as_float(((unsigned)u) << 16);
}

// ---------------------------------------------------------------------------
// Patch gather: Pm[row][c*16+p] = bf16(x[b, i*8+p, c]); cols 112..127 = 0.
// ---------------------------------------------------------------------------
__global__ __launch_bounds__(256) void patch_kernel(
    const float* __restrict__ x, unsigned short* __restrict__ Pm) {
  int idx = blockIdx.x * 256 + threadIdx.x;
  if (idx >= M_ROWS * KEMB) return;
  int row = idx >> 7, c = idx & 127;
  float v = 0.f;
  if (c < 112) {
    int b = row / NPATCH, i = row - b * NPATCH;
    int ci = c >> 4, p = c & 15;
    v = x[((size_t)b * T_LEN + (size_t)i * 8 + p) * C_IN + ci];
  }
  Pm[idx] = f2bf(v);
}

// ---------------------------------------------------------------------------
// W_emb convert: Wt[n][k] = bf16(W_emb[k][n]) for k<112, 0 for k in [112,128).
// ---------------------------------------------------------------------------
__global__ __launch_bounds__(256) void wemb_cvt_kernel(
    const float* __restrict__ W, unsigned short* __restrict__ Wt) {
  int idx = blockIdx.x * 256 + threadIdx.x;
  if (idx >= DIM * KEMB) return;
  int n = idx >> 7, k = idx & 127;
  float v = (k < 112) ? W[(size_t)k * DIM + n] : 0.f;
  Wt[idx] = f2bf(v);
}

// ---------------------------------------------------------------------------
// LayerNorm, 4 rows/block. BF: bf16 vs fp32 out.
// ---------------------------------------------------------------------------
template <bool BF>
__global__ __launch_bounds__(256) void ln_kernel(
    const float* __restrict__ in, const float* __restrict__ g,
    const float* __restrict__ bb, void* __restrict__ outv, int M) {
  int row = blockIdx.x * 4 + (threadIdx.x >> 6);
  if (row >= M) return;
  int lane = threadIdx.x & 63;
  const float* xr = in + (size_t)row * DIM;
  float v[8];
  float s = 0.f;
  #pragma unroll
  for (int k = 0; k < 8; ++k) { v[k] = xr[lane + 64 * k]; s += v[k]; }
  #pragma unroll
  for (int off = 32; off; off >>= 1) s += __shfl_down(s, off);
  s = __shfl(s, 0);
  float mu = s * (1.f / DIM);
  float q = 0.f;
  #pragma unroll
  for (int k = 0; k < 8; ++k) { float d = v[k] - mu; q = fmaf(d, d, q); }
  #pragma unroll
  for (int off = 32; off; off >>= 1) q += __shfl_down(q, off);
  q = __shfl(q, 0);
  float rstd = rsqrtf(q * (1.f / DIM) + LN_EPS);
  #pragma unroll
  for (int k = 0; k < 8; ++k) {
    int d = lane + 64 * k;
    float r = (v[k] - mu) * rstd * g[d] + bb[d];
    if (BF)
      ((unsigned short*)outv)[(size_t)row * DIM + d] = f2bf(r);
    else
      ((float*)outv)[(size_t)row * DIM + d] = r;
  }
}

// ---------------------------------------------------------------------------
// Weight convert + transpose: W[K][N] fp32 -> Wt[N][K] bf16 (per layer z).
// ---------------------------------------------------------------------------
__global__ __launch_bounds__(256) void wcvt_kernel(
    const float* __restrict__ W, unsigned short* __restrict__ Wt, int K, int N) {
  __shared__ float tile[32][33];
  int n0 = blockIdx.x * 32, k0 = blockIdx.y * 32, L = blockIdx.z;
  const float* Ws = W + (size_t)L * K * N;
  unsigned short* Wd = Wt + (size_t)L * K * N;
  int tx = threadIdx.x & 31, ty = threadIdx.x >> 5;
  #pragma unroll
  for (int i = 0; i < 4; ++i)
    tile[ty + i * 8][tx] = Ws[(size_t)(k0 + ty + i * 8) * N + n0 + tx];
  __syncthreads();
  #pragma unroll
  for (int i = 0; i < 4; ++i)
    Wd[(size_t)(n0 + ty + i * 8) * K + k0 + tx] = f2bf(tile[tx][ty + i * 8]);
}

// ---------------------------------------------------------------------------
// RoPE cos/sin table: tab[i*32+j] = (cos, sin) of i * 10000^(-j/32).
// ---------------------------------------------------------------------------
__global__ __launch_bounds__(256) void rope_tab_kernel(float2* __restrict__ tab) {
  int idx = blockIdx.x * 256 + threadIdx.x;
  if (idx >= NPATCH * 32) return;
  int i = idx >> 5, j = idx & 31;
  float inv = powf(10000.0f, -(float)j * (1.0f / 32.0f));
  float sn, cs;
  sincosf((float)i * inv, &sn, &cs);
  tab[idx] = make_float2(cs, sn);
}

// ---------------------------------------------------------------------------
// bf16 MFMA GEMM, TM x TN tile, BK=32, 4 waves (2x2), double-buffered LDS,
// ONE barrier per K-iter. EPI codes as before.
// ---------------------------------------------------------------------------
template <int TM, int TN, int EPI>
__global__ __launch_bounds__(256) void mfma_gemm(
    const unsigned short* __restrict__ A, const unsigned short* __restrict__ Bt,
    const float* __restrict__ bias, const float* __restrict__ res,
    float* __restrict__ Cf, float* __restrict__ Cf2,
    unsigned short* __restrict__ Cb, const float2* __restrict__ rtab,
    int M, int N, int K) {
  constexpr int WM = TM / 2, WN = TN / 2;
  constexpr int NI = WM / 16, NJ = WN / 16;
  constexpr int ACH = TM * 4;               // A uint4 chunks per K-tile
  constexpr int TCH = (TM + TN) * 4;        // total chunks
  constexpr int CH = TCH / 256;             // chunks per thread
  __shared__ __align__(16) unsigned short As[2][TM][40];
  __shared__ __align__(16) unsigned short Bs[2][TN][40];
  const int bm = blockIdx.y * TM;
  const int bn = blockIdx.x * TN;
  const int tid = threadIdx.x;
  const int lane = tid & 63, wave = tid >> 6;
  const int quad = lane >> 4, l16 = lane & 15;
  const int wm = (wave & 1) * WM;
  const int wn = (wave >> 1) * WN;

  float4v acc[NI][NJ];
  #pragma unroll
  for (int i = 0; i < NI; ++i)
    #pragma unroll
    for (int j = 0; j < NJ; ++j)
      acc[i][j] = (float4v){0.f, 0.f, 0.f, 0.f};

  uint4 pr[CH];
  auto load_regs = [&](int kk) {
    #pragma unroll
    for (int it = 0; it < CH; ++it) {
      int c = tid + it * 256;
      if (c < ACH) {
        int row = c >> 2, ch = (c & 3) * 8;
        int gm = bm + row;
        pr[it] = make_uint4(0u, 0u, 0u, 0u);
        if (gm < M) pr[it] = *(const uint4*)(A + (size_t)gm * K + kk + ch);
      } else {
        int c2 = c - ACH;
        int row = c2 >> 2, ch = (c2 & 3) * 8;
        pr[it] = *(const uint4*)(Bt + (size_t)(bn + row) * K + kk + ch);
      }
    }
  };

  load_regs(0);
  int buf = 0;
  for (int k0 = 0; k0 < K; k0 += 32, buf ^= 1) {
    #pragma unroll
    for (int it = 0; it < CH; ++it) {
      int c = tid + it * 256;
      if (c < ACH)
        *(uint4*)&As[buf][c >> 2][(c & 3) * 8] = pr[it];
      else {
        int c2 = c - ACH;
        *(uint4*)&Bs[buf][c2 >> 2][(c2 & 3) * 8] = pr[it];
      }
    }
    if (k0 + 32 < K) load_regs(k0 + 32);   // prefetch; flies across MFMA block
    __syncthreads();
    short8 af[NI], bfr[NJ];
    #pragma unroll
    for (int i = 0; i < NI; ++i)
      af[i] = *(const short8*)&As[buf][wm + i * 16 + l16][quad * 8];
    #pragma unroll
    for (int j = 0; j < NJ; ++j)
      bfr[j] = *(const short8*)&Bs[buf][wn + j * 16 + l16][quad * 8];
    __builtin_amdgcn_s_setprio(1);
    #pragma unroll
    for (int i = 0; i < NI; ++i)
      #pragma unroll
      for (int j = 0; j < NJ; ++j)
        acc[i][j] = __builtin_amdgcn_mfma_f32_16x16x32_bf16(
            af[i], bfr[j], acc[i][j], 0, 0, 0);
    __builtin_amdgcn_s_setprio(0);
    // no trailing barrier: next iter writes the other LDS buffer
  }

  if (EPI == 6) {
    const int sec = (bn + wn) >> 9;   // 0=q, 1=k, 2=v (wave-uniform; WN=64)
    #pragma unroll
    for (int i = 0; i < NI; ++i) {
      int gm0 = bm + wm + i * 16 + quad * 4;
      #pragma unroll
      for (int r = 0; r < 4; ++r) {
        int gm = gm0 + r;
        if (gm >= M) continue;
        size_t rowoff = (size_t)gm * N;
        if (sec < 2) {
          int ip = gm; if (ip >= 2046) ip -= 2046; if (ip >= 1023) ip -= 1023;
          float sc = (sec == 0) ? 0.125f : 1.f;
          #pragma unroll
          for (int j = 0; j < NJ / 2; ++j) {
            int gn = bn + wn + j * 16 + l16;
            float v0 = acc[i][j][r] + bias[gn];
            float v1 = acc[i][j + NJ / 2][r] + bias[gn + 32];
            float2 t = rtab[ip * 32 + j * 16 + l16];
            Cb[rowoff + gn]      = f2bf((v0 * t.x - v1 * t.y) * sc);
            Cb[rowoff + gn + 32] = f2bf((v1 * t.x + v0 * t.y) * sc);
          }
        } else {
          #pragma unroll
          for (int j = 0; j < NJ; ++j) {
            int gn = bn + wn + j * 16 + l16;
            Cb[rowoff + gn] = f2bf(acc[i][j][r] + bias[gn]);
          }
        }
      }
    }
    return;
  }

  #pragma unroll
  for (int j = 0; j < NJ; ++j) {
    int gn = bn + wn + j * 16 + l16;
    float bv = bias[gn];
    #pragma unroll
    for (int i = 0; i < NI; ++i) {
      int gm0 = bm + wm + i * 16 + quad * 4;
      #pragma unroll
      for (int r = 0; r < 4; ++r) {
        int gm = gm0 + r;
        if (gm < M) {
          float v = acc[i][j][r] + bv;
          size_t off = (size_t)gm * N + gn;
          if (EPI == 1) {
            Cf[off] = v + res[off];
          } else if (EPI == 2) {
            Cb[off] = f2bf(0.5f * v * (1.f + erff(v * 0.70710678118f)));
          } else if (EPI == 3) {
            Cb[off] = f2bf(v);
          } else {
            Cf[off] = v;
            Cf2[off] = v;
          }
        }
      }
    }
  }
}

// ---------------------------------------------------------------------------
// MFMA flash attention v5: IN-BLOCK split-K, 8 waves (512 thr), 512 blocks.
//  - Wave pair (wq, wq+4) owns q rows qt0+wq*16..+15; half=wave>>2 takes
//    even/odd 64-key tiles of each 128-key slab. 16 waves/CU (2x R0's 8).
//  - Q: per-lane direct global->reg (no Qs LDS).
//  - K/V: 128-key slab staged per iter by all 512 threads (coalesced K rows;
//    conflict-free packed-b32 V transpose). Single-buffer, 2 barriers/iter,
//    register prefetch flies across compute. 8 iters (vs R0's 16).
//  - defer-max (THR=8) + deferred l-reduction + setprio.
//  - In-block merge of the two (m,l,accO) partials through the dead Ps
//    buffer -> no global combine kernel (R2's failure mode avoided).
//  - XCD swizzle kept (R2: FETCH 34.8->6.2 MB).
// ---------------------------------------------------------------------------
#define APITCH 72

__global__ __launch_bounds__(512, 4) void attn_kernel(
    const unsigned short* __restrict__ qkvb, unsigned short* __restrict__ o) {
  // XCD-aware decode: bid = slot*8 + xcd; (b,h) group = xcd + 8*(slot>>4)
  const int bid = blockIdx.x;
  const int xcd = bid & 7, slot = bid >> 3;
  const int qt0 = (slot & 15) * 64;
  const int gh = xcd + 8 * (slot >> 4);    // 0..31
  const int h = gh & 7, b = gh >> 3;

  const int tid = threadIdx.x;
  const int lane = tid & 63, wave = tid >> 6;
  const int quad = lane >> 4, l16 = lane & 15;
  const int half = wave >> 2, wq = wave & 3;

  __shared__ __align__(16) unsigned short Ks[2][64][APITCH];  // [half][key][d]
  __shared__ __align__(16) unsigned short Vt[2][64][APITCH];  // [half][d][key]
  __shared__ __align__(16) unsigned short Ps[8][16][APITCH];  // per-wave P; reused as merge buf

  // ---- Q A-fragments: per-lane direct global->reg (one-time) ----
  short8 aq0 = {0, 0, 0, 0, 0, 0, 0, 0}, aq1 = aq0;
  {
    int qrow = qt0 + wq * 16 + l16;
    if (qrow < NPATCH) {
      const uint4* qr = (const uint4*)(qkvb + (size_t)(b * NPATCH + qrow) * (3 * DIM) + h * HD + quad * 8);
      aq0 = __builtin_bit_cast(short8, qr[0]);
      aq1 = __builtin_bit_cast(short8, qr[4]);   // +32 shorts
    }
  }

  // ---- K staging: thread covers slab row t>>2, 32B at col (t&3)*16 ----
  const int krow = tid >> 2, kc0 = (tid & 3) * 16;
  // ---- V staging: thread covers slab keys {2*kp2, 2*kp2+1}, dims dg*8.. ----
  const int kp2 = tid & 63, dg = tid >> 6;
  uint4 pk0, pk1, pv0, pv1;
  auto load_kv = [&](int js) {
    pk0 = pk1 = pv0 = pv1 = make_uint4(0u, 0u, 0u, 0u);
    int jk = js + krow;
    if (jk < NPATCH) {
      const unsigned short* kb = qkvb + (size_t)(b * NPATCH + jk) * (3 * DIM) + DIM + h * HD;
      pk0 = *(const uint4*)(kb + kc0);
      pk1 = *(const uint4*)(kb + kc0 + 8);
    }
    int jv = js + 2 * kp2;
    const unsigned short* vb = qkvb + (size_t)(b * NPATCH + jv) * (3 * DIM) + 2 * DIM + h * HD + dg * 8;
    if (jv < NPATCH)     pv0 = *(const uint4*)vb;
    if (jv + 1 < NPATCH) pv1 = *(const uint4*)(vb + 3 * DIM);
  };

  load_kv(0);

  float4v accO[4];
  #pragma unroll
  for (int j2 = 0; j2 < 4; ++j2) accO[j2] = (float4v){0.f, 0.f, 0.f, 0.f};
  float m_run[4] = {-1e30f, -1e30f, -1e30f, -1e30f};
  float lp[4] = {0.f, 0.f, 0.f, 0.f};

  constexpr int NIT = (NPATCH + 127) / 128;   // 8 slabs of 128 keys
  for (int it = 0; it < NIT; ++it) {
    if (it > 0) __syncthreads();   // prev compute done before overwrite
    // stage slab: K rows (coalesced b128) + V transpose (packed b32)
    {
      *(uint4*)&Ks[krow >> 6][krow & 63][kc0] = pk0;
      *(uint4*)&Ks[krow >> 6][krow & 63][kc0 + 8] = pk1;
      unsigned short va[8], vb8[8];
      *(uint4*)&va[0] = pv0;
      *(uint4*)&vb8[0] = pv1;
      const int vh = kp2 >> 5, lp2 = kp2 & 31;
      #pragma unroll
      for (int u = 0; u < 8; ++u) {
        unsigned pk = (unsigned)va[u] | ((unsigned)vb8[u] << 16);
        *(unsigned*)&Vt[vh][dg * 8 + u][2 * lp2] = pk;
      }
    }
    __syncthreads();
    if (it + 1 < NIT) load_kv((it + 1) * 128);   // prefetch flies over compute

    const int j0 = it * 128 + half * 64;

    // QK^T from LDS K (this half's tile)
    float4v s[4];
    __builtin_amdgcn_s_setprio(1);
    #pragma unroll
    for (int j = 0; j < 4; ++j) {
      s[j] = (float4v){0.f, 0.f, 0.f, 0.f};
      short8 bk0 = *(const short8*)&Ks[half][j * 16 + l16][quad * 8];
      short8 bk1 = *(const short8*)&Ks[half][j * 16 + l16][32 + quad * 8];
      s[j] = __builtin_amdgcn_mfma_f32_16x16x32_bf16(aq0, bk0, s[j], 0, 0, 0);
      s[j] = __builtin_amdgcn_mfma_f32_16x16x32_bf16(aq1, bk1, s[j], 0, 0, 0);
    }
    __builtin_amdgcn_s_setprio(0);

    // online softmax with defer-max; deferred l (per-lane partials)
    float mx[4];
    #pragma unroll
    for (int r = 0; r < 4; ++r)
      mx[r] = fmaxf(fmaxf(s[0][r], s[1][r]), fmaxf(s[2][r], s[3][r]));
    #pragma unroll
    for (int mask = 1; mask < 16; mask <<= 1)
      #pragma unroll
      for (int r = 0; r < 4; ++r)
        mx[r] = fmaxf(mx[r], __shfl_xor(mx[r], mask));
    float gmax = fmaxf(fmaxf(mx[0] - m_run[0], mx[1] - m_run[1]),
                       fmaxf(mx[2] - m_run[2], mx[3] - m_run[3]));
    if (!__all(gmax <= 8.f)) {
      #pragma unroll
      for (int r = 0; r < 4; ++r) {
        float mnew = fmaxf(m_run[r], mx[r]);
        float al = __expf(m_run[r] - mnew);
        m_run[r] = mnew;
        lp[r] *= al;
        #pragma unroll
        for (int j2 = 0; j2 < 4; ++j2) accO[j2][r] *= al;
      }
    }
    #pragma unroll
    for (int j = 0; j < 4; ++j) {
      bool valid = (j0 + j * 16 + l16) < NPATCH;
      #pragma unroll
      for (int r = 0; r < 4; ++r) {
        float p = valid ? __expf(s[j][r] - m_run[r]) : 0.f;
        lp[r] += p;
        Ps[wave][quad * 4 + r][j * 16 + l16] = f2bf(p);
      }
    }

    // PV (Ps slice is per-wave private: no barrier needed)
    short8 pa0 = *(const short8*)&Ps[wave][l16][quad * 8];
    short8 pa1 = *(const short8*)&Ps[wave][l16][32 + quad * 8];
    __builtin_amdgcn_s_setprio(1);
    #pragma unroll
    for (int j2 = 0; j2 < 4; ++j2) {
      short8 v0 = *(const short8*)&Vt[half][j2 * 16 + l16][quad * 8];
      short8 v1 = *(const short8*)&Vt[half][j2 * 16 + l16][32 + quad * 8];
      accO[j2] = __builtin_amdgcn_mfma_f32_16x16x32_bf16(pa0, v0, accO[j2], 0, 0, 0);
      accO[j2] = __builtin_amdgcn_mfma_f32_16x16x32_bf16(pa1, v1, accO[j2], 0, 0, 0);
    }
    __builtin_amdgcn_s_setprio(0);
  }

  // deferred l reduction (over the 16 key-lanes)
  #pragma unroll
  for (int mask = 1; mask < 16; mask <<= 1)
    #pragma unroll
    for (int r = 0; r < 4; ++r)
      lp[r] += __shfl_xor(lp[r], mask);

  // ---- in-block merge of the two halves through Ps (dead) ----
  float* Pf = (float*)&Ps[0][0][0];   // 4608 floats available; need 4224
  __syncthreads();                    // all PV reads of Ps done
  if (half == 1) {
    #pragma unroll
    for (int j2 = 0; j2 < 4; ++j2)
      #pragma unroll
      for (int r = 0; r < 4; ++r)
        Pf[((wq * 64 + lane) << 4) + j2 * 4 + r] = accO[j2][r];
    if (l16 == 0) {
      #pragma unroll
      for (int r = 0; r < 4; ++r) {
        Pf[4096 + ((wq * 16 + quad * 4 + r) << 1)]     = m_run[r];
        Pf[4096 + ((wq * 16 + quad * 4 + r) << 1) + 1] = lp[r];
      }
    }
  }
  __syncthreads();
  if (half == 0) {
    #pragma unroll
    for (int r = 0; r < 4; ++r) {
      float m1 = Pf[4096 + ((wq * 16 + quad * 4 + r) << 1)];
      float l1 = Pf[4096 + ((wq * 16 + quad * 4 + r) << 1) + 1];
      float M = fmaxf(m_run[r], m1);
      float w0 = __expf(m_run[r] - M), w1 = __expf(m1 - M);
      float inv = 1.f / (w0 * lp[r] + w1 * l1);
      int qi = qt0 + wq * 16 + quad * 4 + r;
      if (qi < NPATCH) {
        size_t off = (size_t)(b * NPATCH + qi) * DIM + h * HD + l16;
        #pragma unroll
        for (int j2 = 0; j2 < 4; ++j2) {
          float a1 = Pf[((wq * 64 + lane) << 4) + j2 * 4 + r];
          o[off + j2 * 16] = f2bf((w0 * accO[j2][r] + w1 * a1) * inv);
        }
      }
    }
  }
}

// ---------------------------------------------------------------------------
extern "C" void kernel_launch(void* const* d_in, const int* in_sizes, int n_in,
                              void* d_out, int out_size, void* d_ws, size_t ws_size,
                              hipStream_t stream) {
  const float* x      = (const float*)d_in[0];
  const float* W_emb  = (const float*)d_in[1];
  const float* b_emb  = (const float*)d_in[2];
  const float* ln1_g  = (const float*)d_in[3];
  const float* ln1_b  = (const float*)d_in[4];
  const float* W_qkv  = (const float*)d_in[5];
  const float* b_qkv  = (const float*)d_in[6];
  const float* W_proj = (const float*)d_in[7];
  const float* b_proj = (const float*)d_in[8];
  const float* ln2_g  = (const float*)d_in[9];
  const float* ln2_b  = (const float*)d_in[10];
  const float* W_mlp1 = (const float*)d_in[11];
  const float* b_mlp1 = (const float*)d_in[12];
  const float* W_mlp2 = (const float*)d_in[13];
  const float* b_mlp2 = (const float*)d_in[14];
  const float* lnf_g  = (const float*)d_in[15];
  const float* lnf_b  = (const float*)d_in[16];
  float* out = (float*)d_out;

  float* h              = (float*)d_ws;
  unsigned short* qkvb  = (unsigned short*)(h + (size_t)M_ROWS * DIM);
  unsigned short* midbf = qkvb;   // alias: qkvb dead after attn
  unsigned short* ybf   = qkvb + (size_t)M_ROWS * MLP_HID;
  unsigned short* obf   = ybf;    // alias: ybf dead after its GEMM
  unsigned short* wqkv_t  = ybf + (size_t)M_ROWS * DIM;
  unsigned short* wproj_t = wqkv_t  + (size_t)NLAYERS * DIM * 3 * DIM;
  unsigned short* wmlp1_t = wproj_t + (size_t)NLAYERS * DIM * DIM;
  unsigned short* wmlp2_t = wmlp1_t + (size_t)NLAYERS * DIM * MLP_HID;
  float2* rtab = (float2*)(wmlp2_t + (size_t)NLAYERS * MLP_HID * DIM);
  unsigned short* Pm    = (unsigned short*)(rtab + (size_t)NPATCH * 32);
  unsigned short* Wembt = Pm + (size_t)M_ROWS * KEMB;

  wcvt_kernel<<<dim3(3 * DIM / 32, DIM / 32, NLAYERS), 256, 0, stream>>>(W_qkv,  wqkv_t,  DIM, 3 * DIM);
  wcvt_kernel<<<dim3(DIM / 32, DIM / 32, NLAYERS),     256, 0, stream>>>(W_proj, wproj_t, DIM, DIM);
  wcvt_kernel<<<dim3(MLP_HID / 32, DIM / 32, NLAYERS), 256, 0, stream>>>(W_mlp1, wmlp1_t, DIM, MLP_HID);
  wcvt_kernel<<<dim3(DIM / 32, MLP_HID / 32, NLAYERS), 256, 0, stream>>>(W_mlp2, wmlp2_t, MLP_HID, DIM);
  rope_tab_kernel<<<(NPATCH * 32 + 255) / 256, 256, 0, stream>>>(rtab);
  patch_kernel<<<(M_ROWS * KEMB + 255) / 256, 256, 0, stream>>>(x, Pm);
  wemb_cvt_kernel<<<(DIM * KEMB + 255) / 256, 256, 0, stream>>>(W_emb, Wembt);

  const int MT64 = (M_ROWS + 63) / 64;     // 64
  const int MT128 = (M_ROWS + 127) / 128;  // 32
  const int LNG = (M_ROWS + 3) / 4;        // 1023

  // embed: out & h = Pm @ Wembt^T + b_emb  (TN=64: 512 blocks)
  mfma_gemm<64, 64, 5><<<dim3(DIM / 64, MT64), 256, 0, stream>>>(
      Pm, Wembt, b_emb, nullptr, out, h, nullptr, nullptr, M_ROWS, DIM, KEMB);

  for (int L = 0; L < NLAYERS; ++L) {
    ln_kernel<true><<<LNG, 256, 0, stream>>>(h, ln1_g + L * DIM, ln1_b + L * DIM, ybf, M_ROWS);
    // qkv with fused RoPE (128x128 tiles: 12x32 = 384 blocks)
    mfma_gemm<128, 128, 6><<<dim3(3 * DIM / 128, MT128), 256, 0, stream>>>(
        ybf, wqkv_t + (size_t)L * DIM * 3 * DIM, b_qkv + L * 3 * DIM,
        nullptr, nullptr, nullptr, qkvb, rtab, M_ROWS, 3 * DIM, DIM);
    attn_kernel<<<dim3(512), 512, 0, stream>>>(qkvb, obf);
    // proj: h += o @ Wp + bias  (64x64: 512 blocks)
    mfma_gemm<64, 64, 1><<<dim3(DIM / 64, MT64), 256, 0, stream>>>(
        obf, wproj_t + (size_t)L * DIM * DIM, b_proj + L * DIM,
        h, h, nullptr, nullptr, nullptr, M_ROWS, DIM, DIM);
    ln_kernel<true><<<LNG, 256, 0, stream>>>(h, ln2_g + L * DIM, ln2_b + L * DIM, ybf, M_ROWS);
    // mlp1 + GELU (128x128 tiles: 16x32 = 512 blocks)
    mfma_gemm<128, 128, 2><<<dim3(MLP_HID / 128, MT128), 256, 0, stream>>>(
        ybf, wmlp1_t + (size_t)L * DIM * MLP_HID, b_mlp1 + L * MLP_HID,
        nullptr, nullptr, nullptr, midbf, nullptr, M_ROWS, MLP_HID, DIM);
    // mlp2: h += mid @ Wm2 + bias  (64x64: 512 blocks)
    mfma_gemm<64, 64, 1><<<dim3(DIM / 64, MT64), 256, 0, stream>>>(
        midbf, wmlp2_t + (size_t)L * MLP_HID * DIM, b_mlp2 + L * DIM,
        h, h, nullptr, nullptr, nullptr, M_ROWS, DIM, MLP_HID);
  }

  ln_kernel<false><<<LNG, 256, 0, stream>>>(h, lnf_g, lnf_b, out + (size_t)M_ROWS * DIM, M_ROWS);
}

// Round 5
// 644.160 us; speedup vs baseline: 1.1877x; 1.0616x over previous
//
#include <hip/hip_runtime.h>
#include <hip/hip_bf16.h>
#include <math.h>

#define B_SZ 4
#define T_LEN 8192
#define C_IN 7
#define NPATCH 1023
#define DIM 512
#define NH 8
#define HD 64
#define NLAYERS 4
#define MLP_HID 2048
#define M_ROWS (B_SZ * NPATCH)   // 4092
#define KEMB 128                 // padded patch length (112 real + 16 zero)
#define LN_EPS 1e-5f

typedef __attribute__((ext_vector_type(8))) short short8;
typedef __attribute__((ext_vector_type(4))) float float4v;

static __device__ __forceinline__ unsigned short f2bf(float f) {
  __hip_bfloat16 h = __float2bfloat16(f);
  return *reinterpret_cast<unsigned short*>(&h);
}
static __device__ __forceinline__ float bf2f(unsigned short u) {
  return __uint_as_float(((unsigned)u) << 16);
}

// async global->LDS DMA, 16B per lane (wave-uniform LDS base + lane*16)
static __device__ __forceinline__ void gload_lds16(const void* g, void* l) {
  __builtin_amdgcn_global_load_lds(
      (const __attribute__((address_space(1))) unsigned int*)g,
      (__attribute__((address_space(3))) unsigned int*)l, 16, 0, 0);
}

// ---------------------------------------------------------------------------
// Patch gather: Pm[row][c*16+p] = bf16(x[b, i*8+p, c]); cols 112..127 = 0.
// ---------------------------------------------------------------------------
__global__ __launch_bounds__(256) void patch_kernel(
    const float* __restrict__ x, unsigned short* __restrict__ Pm) {
  int idx = blockIdx.x * 256 + threadIdx.x;
  if (idx >= M_ROWS * KEMB) return;
  int row = idx >> 7, c = idx & 127;
  float v = 0.f;
  if (c < 112) {
    int b = row / NPATCH, i = row - b * NPATCH;
    int ci = c >> 4, p = c & 15;
    v = x[((size_t)b * T_LEN + (size_t)i * 8 + p) * C_IN + ci];
  }
  Pm[idx] = f2bf(v);
}

// ---------------------------------------------------------------------------
// W_emb convert: Wt[n][k] = bf16(W_emb[k][n]) for k<112, 0 for k in [112,128).
// ---------------------------------------------------------------------------
__global__ __launch_bounds__(256) void wemb_cvt_kernel(
    const float* __restrict__ W, unsigned short* __restrict__ Wt) {
  int idx = blockIdx.x * 256 + threadIdx.x;
  if (idx >= DIM * KEMB) return;
  int n = idx >> 7, k = idx & 127;
  float v = (k < 112) ? W[(size_t)k * DIM + n] : 0.f;
  Wt[idx] = f2bf(v);
}

// ---------------------------------------------------------------------------
// LayerNorm, 4 rows/block. BF: bf16 vs fp32 out.
// ---------------------------------------------------------------------------
template <bool BF>
__global__ __launch_bounds__(256) void ln_kernel(
    const float* __restrict__ in, const float* __restrict__ g,
    const float* __restrict__ bb, void* __restrict__ outv, int M) {
  int row = blockIdx.x * 4 + (threadIdx.x >> 6);
  if (row >= M) return;
  int lane = threadIdx.x & 63;
  const float* xr = in + (size_t)row * DIM;
  float v[8];
  float s = 0.f;
  #pragma unroll
  for (int k = 0; k < 8; ++k) { v[k] = xr[lane + 64 * k]; s += v[k]; }
  #pragma unroll
  for (int off = 32; off; off >>= 1) s += __shfl_down(s, off);
  s = __shfl(s, 0);
  float mu = s * (1.f / DIM);
  float q = 0.f;
  #pragma unroll
  for (int k = 0; k < 8; ++k) { float d = v[k] - mu; q = fmaf(d, d, q); }
  #pragma unroll
  for (int off = 32; off; off >>= 1) q += __shfl_down(q, off);
  q = __shfl(q, 0);
  float rstd = rsqrtf(q * (1.f / DIM) + LN_EPS);
  #pragma unroll
  for (int k = 0; k < 8; ++k) {
    int d = lane + 64 * k;
    float r = (v[k] - mu) * rstd * g[d] + bb[d];
    if (BF)
      ((unsigned short*)outv)[(size_t)row * DIM + d] = f2bf(r);
    else
      ((float*)outv)[(size_t)row * DIM + d] = r;
  }
}

// ---------------------------------------------------------------------------
// Weight convert + transpose: W[K][N] fp32 -> Wt[N][K] bf16 (per layer z).
// ---------------------------------------------------------------------------
__global__ __launch_bounds__(256) void wcvt_kernel(
    const float* __restrict__ W, unsigned short* __restrict__ Wt, int K, int N) {
  __shared__ float tile[32][33];
  int n0 = blockIdx.x * 32, k0 = blockIdx.y * 32, L = blockIdx.z;
  const float* Ws = W + (size_t)L * K * N;
  unsigned short* Wd = Wt + (size_t)L * K * N;
  int tx = threadIdx.x & 31, ty = threadIdx.x >> 5;
  #pragma unroll
  for (int i = 0; i < 4; ++i)
    tile[ty + i * 8][tx] = Ws[(size_t)(k0 + ty + i * 8) * N + n0 + tx];
  __syncthreads();
  #pragma unroll
  for (int i = 0; i < 4; ++i)
    Wd[(size_t)(n0 + ty + i * 8) * K + k0 + tx] = f2bf(tile[tx][ty + i * 8]);
}

// ---------------------------------------------------------------------------
// RoPE cos/sin table: tab[i*32+j] = (cos, sin) of i * 10000^(-j/32).
// ---------------------------------------------------------------------------
__global__ __launch_bounds__(256) void rope_tab_kernel(float2* __restrict__ tab) {
  int idx = blockIdx.x * 256 + threadIdx.x;
  if (idx >= NPATCH * 32) return;
  int i = idx >> 5, j = idx & 31;
  float inv = powf(10000.0f, -(float)j * (1.0f / 32.0f));
  float sn, cs;
  sincosf((float)i * inv, &sn, &cs);
  tab[idx] = make_float2(cs, sn);
}

// ---------------------------------------------------------------------------
// bf16 MFMA GEMM v2: global_load_lds (DMA) staging, m97 structure.
//  - LDS linear [2][T][32] (no pad); 16B-chunk XOR swizzle (both sides):
//    LDS[row][s] holds global chunk s ^ ((row>>1)&3); reader uses
//    slot = quad ^ ((l16>>1)&3). ds_read_b128 conflicts: 2-way (free).
//  - Schedule: stage(t0) -> { sync (drain DMA; all chunks visible; other
//    buffer free) -> issue DMA tile k+1 into buf^1 -> ds_read+MFMA buf }.
//    Next-tile DMA flies across the MFMA block; drained at next barrier.
//  - A rows are NOT predicated (DMA can't): OOB rows (<= 4 past M) read
//    mapped workspace slack; garbage only reaches acc rows never stored.
// EPI: 1 = bias + res -> fp32 (res==Cf ok: h += ...);
//      2 = bias + GELU -> bf16; 3 = bias -> bf16;
//      5 = bias -> fp32 to BOTH Cf and Cf2 (embed);
//      6 = bias + RoPE (q scaled 1/8) -> bf16 (qkv; needs WN=64).
// ---------------------------------------------------------------------------
template <int TM, int TN, int EPI>
__global__ __launch_bounds__(256) void mfma_gemm(
    const unsigned short* __restrict__ A, const unsigned short* __restrict__ Bt,
    const float* __restrict__ bias, const float* __restrict__ res,
    float* __restrict__ Cf, float* __restrict__ Cf2,
    unsigned short* __restrict__ Cb, const float2* __restrict__ rtab,
    int M, int N, int K) {
  constexpr int WM = TM / 2, WN = TN / 2;
  constexpr int NI = WM / 16, NJ = WN / 16;
  constexpr int NCH = (TM + TN) / 16;       // 1 KB DMA chunks per K-step
  constexpr int CPW = NCH / 4;              // chunks per wave
  __shared__ __align__(16) unsigned short As[2][TM][32];
  __shared__ __align__(16) unsigned short Bs[2][TN][32];
  const int bm = blockIdx.y * TM;
  const int bn = blockIdx.x * TN;
  const int tid = threadIdx.x;
  const int lane = tid & 63, wave = tid >> 6;
  const int quad = lane >> 4, l16 = lane & 15;
  const int wm = (wave & 1) * WM;
  const int wn = (wave >> 1) * WN;
  const int lrow4 = lane >> 2, lc = lane & 3;   // DMA source decomposition
  const int rslot = quad ^ ((l16 >> 1) & 3);    // read-side swizzled slot

  float4v acc[NI][NJ];
  #pragma unroll
  for (int i = 0; i < NI; ++i)
    #pragma unroll
    for (int j = 0; j < NJ; ++j)
      acc[i][j] = (float4v){0.f, 0.f, 0.f, 0.f};

  auto stage = [&](int bufI, int kk) {
    #pragma unroll
    for (int it = 0; it < CPW; ++it) {
      int c = wave * CPW + it;
      if (c < TM / 16) {
        int row = c * 16 + lrow4;
        int col16 = lc ^ ((row >> 1) & 3);
        gload_lds16(A + (size_t)(bm + row) * K + kk + col16 * 8,
                    &As[bufI][c * 16][0]);
      } else {
        int c2 = c - TM / 16;
        int row = c2 * 16 + lrow4;
        int col16 = lc ^ ((row >> 1) & 3);
        gload_lds16(Bt + (size_t)(bn + row) * K + kk + col16 * 8,
                    &Bs[bufI][c2 * 16][0]);
      }
    }
  };

  stage(0, 0);
  int buf = 0;
  for (int k0 = 0; k0 < K; k0 += 32, buf ^= 1) {
    __syncthreads();   // drains own DMA (vmcnt 0) + barrier: tile visible, other buf free
    if (k0 + 32 < K) stage(buf ^ 1, k0 + 32);   // DMA flies across MFMA block
    short8 af[NI], bfr[NJ];
    #pragma unroll
    for (int i = 0; i < NI; ++i)
      af[i] = *(const short8*)&As[buf][wm + i * 16 + l16][rslot * 8];
    #pragma unroll
    for (int j = 0; j < NJ; ++j)
      bfr[j] = *(const short8*)&Bs[buf][wn + j * 16 + l16][rslot * 8];
    __builtin_amdgcn_s_setprio(1);
    #pragma unroll
    for (int i = 0; i < NI; ++i)
      #pragma unroll
      for (int j = 0; j < NJ; ++j)
        acc[i][j] = __builtin_amdgcn_mfma_f32_16x16x32_bf16(
            af[i], bfr[j], acc[i][j], 0, 0, 0);
    __builtin_amdgcn_s_setprio(0);
  }

  if (EPI == 6) {
    const int sec = (bn + wn) >> 9;   // 0=q, 1=k, 2=v (wave-uniform; WN=64)
    #pragma unroll
    for (int i = 0; i < NI; ++i) {
      int gm0 = bm + wm + i * 16 + quad * 4;
      #pragma unroll
      for (int r = 0; r < 4; ++r) {
        int gm = gm0 + r;
        if (gm >= M) continue;
        size_t rowoff = (size_t)gm * N;
        if (sec < 2) {
          int ip = gm; if (ip >= 2046) ip -= 2046; if (ip >= 1023) ip -= 1023;
          float sc = (sec == 0) ? 0.125f : 1.f;
          #pragma unroll
          for (int j = 0; j < NJ / 2; ++j) {
            int gn = bn + wn + j * 16 + l16;
            float v0 = acc[i][j][r] + bias[gn];
            float v1 = acc[i][j + NJ / 2][r] + bias[gn + 32];
            float2 t = rtab[ip * 32 + j * 16 + l16];
            Cb[rowoff + gn]      = f2bf((v0 * t.x - v1 * t.y) * sc);
            Cb[rowoff + gn + 32] = f2bf((v1 * t.x + v0 * t.y) * sc);
          }
        } else {
          #pragma unroll
          for (int j = 0; j < NJ; ++j) {
            int gn = bn + wn + j * 16 + l16;
            Cb[rowoff + gn] = f2bf(acc[i][j][r] + bias[gn]);
          }
        }
      }
    }
    return;
  }

  #pragma unroll
  for (int j = 0; j < NJ; ++j) {
    int gn = bn + wn + j * 16 + l16;
    float bv = bias[gn];
    #pragma unroll
    for (int i = 0; i < NI; ++i) {
      int gm0 = bm + wm + i * 16 + quad * 4;
      #pragma unroll
      for (int r = 0; r < 4; ++r) {
        int gm = gm0 + r;
        if (gm < M) {
          float v = acc[i][j][r] + bv;
          size_t off = (size_t)gm * N + gn;
          if (EPI == 1) {
            Cf[off] = v + res[off];
          } else if (EPI == 2) {
            Cb[off] = f2bf(0.5f * v * (1.f + erff(v * 0.70710678118f)));
          } else if (EPI == 3) {
            Cb[off] = f2bf(v);
          } else {
            Cf[off] = v;
            Cf2[off] = v;
          }
        }
      }
    }
  }
}

// ---------------------------------------------------------------------------
// MFMA flash attention v5 (unchanged from R4): IN-BLOCK split-K, 8 waves.
// ---------------------------------------------------------------------------
#define APITCH 72

__global__ __launch_bounds__(512, 4) void attn_kernel(
    const unsigned short* __restrict__ qkvb, unsigned short* __restrict__ o) {
  const int bid = blockIdx.x;
  const int xcd = bid & 7, slot = bid >> 3;
  const int qt0 = (slot & 15) * 64;
  const int gh = xcd + 8 * (slot >> 4);    // 0..31
  const int h = gh & 7, b = gh >> 3;

  const int tid = threadIdx.x;
  const int lane = tid & 63, wave = tid >> 6;
  const int quad = lane >> 4, l16 = lane & 15;
  const int half = wave >> 2, wq = wave & 3;

  __shared__ __align__(16) unsigned short Ks[2][64][APITCH];  // [half][key][d]
  __shared__ __align__(16) unsigned short Vt[2][64][APITCH];  // [half][d][key]
  __shared__ __align__(16) unsigned short Ps[8][16][APITCH];  // per-wave P; reused as merge buf

  // ---- Q A-fragments: per-lane direct global->reg (one-time) ----
  short8 aq0 = {0, 0, 0, 0, 0, 0, 0, 0}, aq1 = aq0;
  {
    int qrow = qt0 + wq * 16 + l16;
    if (qrow < NPATCH) {
      const uint4* qr = (const uint4*)(qkvb + (size_t)(b * NPATCH + qrow) * (3 * DIM) + h * HD + quad * 8);
      aq0 = __builtin_bit_cast(short8, qr[0]);
      aq1 = __builtin_bit_cast(short8, qr[4]);   // +32 shorts
    }
  }

  const int krow = tid >> 2, kc0 = (tid & 3) * 16;
  const int kp2 = tid & 63, dg = tid >> 6;
  uint4 pk0, pk1, pv0, pv1;
  auto load_kv = [&](int js) {
    pk0 = pk1 = pv0 = pv1 = make_uint4(0u, 0u, 0u, 0u);
    int jk = js + krow;
    if (jk < NPATCH) {
      const unsigned short* kb = qkvb + (size_t)(b * NPATCH + jk) * (3 * DIM) + DIM + h * HD;
      pk0 = *(const uint4*)(kb + kc0);
      pk1 = *(const uint4*)(kb + kc0 + 8);
    }
    int jv = js + 2 * kp2;
    const unsigned short* vb = qkvb + (size_t)(b * NPATCH + jv) * (3 * DIM) + 2 * DIM + h * HD + dg * 8;
    if (jv < NPATCH)     pv0 = *(const uint4*)vb;
    if (jv + 1 < NPATCH) pv1 = *(const uint4*)(vb + 3 * DIM);
  };

  load_kv(0);

  float4v accO[4];
  #pragma unroll
  for (int j2 = 0; j2 < 4; ++j2) accO[j2] = (float4v){0.f, 0.f, 0.f, 0.f};
  float m_run[4] = {-1e30f, -1e30f, -1e30f, -1e30f};
  float lp[4] = {0.f, 0.f, 0.f, 0.f};

  constexpr int NIT = (NPATCH + 127) / 128;   // 8 slabs of 128 keys
  for (int it = 0; it < NIT; ++it) {
    if (it > 0) __syncthreads();   // prev compute done before overwrite
    {
      *(uint4*)&Ks[krow >> 6][krow & 63][kc0] = pk0;
      *(uint4*)&Ks[krow >> 6][krow & 63][kc0 + 8] = pk1;
      unsigned short va[8], vb8[8];
      *(uint4*)&va[0] = pv0;
      *(uint4*)&vb8[0] = pv1;
      const int vh = kp2 >> 5, lp2 = kp2 & 31;
      #pragma unroll
      for (int u = 0; u < 8; ++u) {
        unsigned pk = (unsigned)va[u] | ((unsigned)vb8[u] << 16);
        *(unsigned*)&Vt[vh][dg * 8 + u][2 * lp2] = pk;
      }
    }
    __syncthreads();
    if (it + 1 < NIT) load_kv((it + 1) * 128);   // prefetch flies over compute

    const int j0 = it * 128 + half * 64;

    float4v s[4];
    __builtin_amdgcn_s_setprio(1);
    #pragma unroll
    for (int j = 0; j < 4; ++j) {
      s[j] = (float4v){0.f, 0.f, 0.f, 0.f};
      short8 bk0 = *(const short8*)&Ks[half][j * 16 + l16][quad * 8];
      short8 bk1 = *(const short8*)&Ks[half][j * 16 + l16][32 + quad * 8];
      s[j] = __builtin_amdgcn_mfma_f32_16x16x32_bf16(aq0, bk0, s[j], 0, 0, 0);
      s[j] = __builtin_amdgcn_mfma_f32_16x16x32_bf16(aq1, bk1, s[j], 0, 0, 0);
    }
    __builtin_amdgcn_s_setprio(0);

    float mx[4];
    #pragma unroll
    for (int r = 0; r < 4; ++r)
      mx[r] = fmaxf(fmaxf(s[0][r], s[1][r]), fmaxf(s[2][r], s[3][r]));
    #pragma unroll
    for (int mask = 1; mask < 16; mask <<= 1)
      #pragma unroll
      for (int r = 0; r < 4; ++r)
        mx[r] = fmaxf(mx[r], __shfl_xor(mx[r], mask));
    float gmax = fmaxf(fmaxf(mx[0] - m_run[0], mx[1] - m_run[1]),
                       fmaxf(mx[2] - m_run[2], mx[3] - m_run[3]));
    if (!__all(gmax <= 8.f)) {
      #pragma unroll
      for (int r = 0; r < 4; ++r) {
        float mnew = fmaxf(m_run[r], mx[r]);
        float al = __expf(m_run[r] - mnew);
        m_run[r] = mnew;
        lp[r] *= al;
        #pragma unroll
        for (int j2 = 0; j2 < 4; ++j2) accO[j2][r] *= al;
      }
    }
    #pragma unroll
    for (int j = 0; j < 4; ++j) {
      bool valid = (j0 + j * 16 + l16) < NPATCH;
      #pragma unroll
      for (int r = 0; r < 4; ++r) {
        float p = valid ? __expf(s[j][r] - m_run[r]) : 0.f;
        lp[r] += p;
        Ps[wave][quad * 4 + r][j * 16 + l16] = f2bf(p);
      }
    }

    short8 pa0 = *(const short8*)&Ps[wave][l16][quad * 8];
    short8 pa1 = *(const short8*)&Ps[wave][l16][32 + quad * 8];
    __builtin_amdgcn_s_setprio(1);
    #pragma unroll
    for (int j2 = 0; j2 < 4; ++j2) {
      short8 v0 = *(const short8*)&Vt[half][j2 * 16 + l16][quad * 8];
      short8 v1 = *(const short8*)&Vt[half][j2 * 16 + l16][32 + quad * 8];
      accO[j2] = __builtin_amdgcn_mfma_f32_16x16x32_bf16(pa0, v0, accO[j2], 0, 0, 0);
      accO[j2] = __builtin_amdgcn_mfma_f32_16x16x32_bf16(pa1, v1, accO[j2], 0, 0, 0);
    }
    __builtin_amdgcn_s_setprio(0);
  }

  #pragma unroll
  for (int mask = 1; mask < 16; mask <<= 1)
    #pragma unroll
    for (int r = 0; r < 4; ++r)
      lp[r] += __shfl_xor(lp[r], mask);

  // ---- in-block merge of the two halves through Ps (dead) ----
  float* Pf = (float*)&Ps[0][0][0];
  __syncthreads();
  if (half == 1) {
    #pragma unroll
    for (int j2 = 0; j2 < 4; ++j2)
      #pragma unroll
      for (int r = 0; r < 4; ++r)
        Pf[((wq * 64 + lane) << 4) + j2 * 4 + r] = accO[j2][r];
    if (l16 == 0) {
      #pragma unroll
      for (int r = 0; r < 4; ++r) {
        Pf[4096 + ((wq * 16 + quad * 4 + r) << 1)]     = m_run[r];
        Pf[4096 + ((wq * 16 + quad * 4 + r) << 1) + 1] = lp[r];
      }
    }
  }
  __syncthreads();
  if (half == 0) {
    #pragma unroll
    for (int r = 0; r < 4; ++r) {
      float m1 = Pf[4096 + ((wq * 16 + quad * 4 + r) << 1)];
      float l1 = Pf[4096 + ((wq * 16 + quad * 4 + r) << 1) + 1];
      float M = fmaxf(m_run[r], m1);
      float w0 = __expf(m_run[r] - M), w1 = __expf(m1 - M);
      float inv = 1.f / (w0 * lp[r] + w1 * l1);
      int qi = qt0 + wq * 16 + quad * 4 + r;
      if (qi < NPATCH) {
        size_t off = (size_t)(b * NPATCH + qi) * DIM + h * HD + l16;
        #pragma unroll
        for (int j2 = 0; j2 < 4; ++j2) {
          float a1 = Pf[((wq * 64 + lane) << 4) + j2 * 4 + r];
          o[off + j2 * 16] = f2bf((w0 * accO[j2][r] + w1 * a1) * inv);
        }
      }
    }
  }
}

// ---------------------------------------------------------------------------
extern "C" void kernel_launch(void* const* d_in, const int* in_sizes, int n_in,
                              void* d_out, int out_size, void* d_ws, size_t ws_size,
                              hipStream_t stream) {
  const float* x      = (const float*)d_in[0];
  const float* W_emb  = (const float*)d_in[1];
  const float* b_emb  = (const float*)d_in[2];
  const float* ln1_g  = (const float*)d_in[3];
  const float* ln1_b  = (const float*)d_in[4];
  const float* W_qkv  = (const float*)d_in[5];
  const float* b_qkv  = (const float*)d_in[6];
  const float* W_proj = (const float*)d_in[7];
  const float* b_proj = (const float*)d_in[8];
  const float* ln2_g  = (const float*)d_in[9];
  const float* ln2_b  = (const float*)d_in[10];
  const float* W_mlp1 = (const float*)d_in[11];
  const float* b_mlp1 = (const float*)d_in[12];
  const float* W_mlp2 = (const float*)d_in[13];
  const float* b_mlp2 = (const float*)d_in[14];
  const float* lnf_g  = (const float*)d_in[15];
  const float* lnf_b  = (const float*)d_in[16];
  float* out = (float*)d_out;

  float* h              = (float*)d_ws;
  unsigned short* qkvb  = (unsigned short*)(h + (size_t)M_ROWS * DIM);
  unsigned short* midbf = qkvb;   // alias: qkvb dead after attn
  unsigned short* ybf   = qkvb + (size_t)M_ROWS * MLP_HID;
  unsigned short* obf   = ybf;    // alias: ybf dead after its GEMM
  unsigned short* wqkv_t  = ybf + (size_t)M_ROWS * DIM;
  unsigned short* wproj_t = wqkv_t  + (size_t)NLAYERS * DIM * 3 * DIM;
  unsigned short* wmlp1_t = wproj_t + (size_t)NLAYERS * DIM * DIM;
  unsigned short* wmlp2_t = wmlp1_t + (size_t)NLAYERS * DIM * MLP_HID;
  float2* rtab = (float2*)(wmlp2_t + (size_t)NLAYERS * MLP_HID * DIM);
  unsigned short* Pm    = (unsigned short*)(rtab + (size_t)NPATCH * 32);
  unsigned short* Wembt = Pm + (size_t)M_ROWS * KEMB;

  wcvt_kernel<<<dim3(3 * DIM / 32, DIM / 32, NLAYERS), 256, 0, stream>>>(W_qkv,  wqkv_t,  DIM, 3 * DIM);
  wcvt_kernel<<<dim3(DIM / 32, DIM / 32, NLAYERS),     256, 0, stream>>>(W_proj, wproj_t, DIM, DIM);
  wcvt_kernel<<<dim3(MLP_HID / 32, DIM / 32, NLAYERS), 256, 0, stream>>>(W_mlp1, wmlp1_t, DIM, MLP_HID);
  wcvt_kernel<<<dim3(DIM / 32, MLP_HID / 32, NLAYERS), 256, 0, stream>>>(W_mlp2, wmlp2_t, MLP_HID, DIM);
  rope_tab_kernel<<<(NPATCH * 32 + 255) / 256, 256, 0, stream>>>(rtab);
  patch_kernel<<<(M_ROWS * KEMB + 255) / 256, 256, 0, stream>>>(x, Pm);
  wemb_cvt_kernel<<<(DIM * KEMB + 255) / 256, 256, 0, stream>>>(W_emb, Wembt);

  const int MT64 = (M_ROWS + 63) / 64;     // 64
  const int MT128 = (M_ROWS + 127) / 128;  // 32
  const int LNG = (M_ROWS + 3) / 4;        // 1023

  // embed: out & h = Pm @ Wembt^T + b_emb  (TN=64: 512 blocks)
  mfma_gemm<64, 64, 5><<<dim3(DIM / 64, MT64), 256, 0, stream>>>(
      Pm, Wembt, b_emb, nullptr, out, h, nullptr, nullptr, M_ROWS, DIM, KEMB);

  for (int L = 0; L < NLAYERS; ++L) {
    ln_kernel<true><<<LNG, 256, 0, stream>>>(h, ln1_g + L * DIM, ln1_b + L * DIM, ybf, M_ROWS);
    // qkv with fused RoPE (128x128 tiles: 12x32 = 384 blocks)
    mfma_gemm<128, 128, 6><<<dim3(3 * DIM / 128, MT128), 256, 0, stream>>>(
        ybf, wqkv_t + (size_t)L * DIM * 3 * DIM, b_qkv + L * 3 * DIM,
        nullptr, nullptr, nullptr, qkvb, rtab, M_ROWS, 3 * DIM, DIM);
    attn_kernel<<<dim3(512), 512, 0, stream>>>(qkvb, obf);
    // proj: h += o @ Wp + bias  (64x64: 512 blocks)
    mfma_gemm<64, 64, 1><<<dim3(DIM / 64, MT64), 256, 0, stream>>>(
        obf, wproj_t + (size_t)L * DIM * DIM, b_proj + L * DIM,
        h, h, nullptr, nullptr, nullptr, M_ROWS, DIM, DIM);
    ln_kernel<true><<<LNG, 256, 0, stream>>>(h, ln2_g + L * DIM, ln2_b + L * DIM, ybf, M_ROWS);
    // mlp1 + GELU (128x128 tiles: 16x32 = 512 blocks)
    mfma_gemm<128, 128, 2><<<dim3(MLP_HID / 128, MT128), 256, 0, stream>>>(
        ybf, wmlp1_t + (size_t)L * DIM * MLP_HID, b_mlp1 + L * MLP_HID,
        nullptr, nullptr, nullptr, midbf, nullptr, M_ROWS, MLP_HID, DIM);
    // mlp2: h += mid @ Wm2 + bias  (64x64: 512 blocks)
    mfma_gemm<64, 64, 1><<<dim3(DIM / 64, MT64), 256, 0, stream>>>(
        midbf, wmlp2_t + (size_t)L * MLP_HID * DIM, b_mlp2 + L * DIM,
        h, h, nullptr, nullptr, nullptr, M_ROWS, DIM, MLP_HID);
  }

  ln_kernel<false><<<LNG, 256, 0, stream>>>(h, lnf_g, lnf_b, out + (size_t)M_ROWS * DIM, M_ROWS);
}

// Round 6
// 612.324 us; speedup vs baseline: 1.2494x; 1.0520x over previous
//
#include <hip/hip_runtime.h>
#include <hip/hip_bf16.h>
#include <math.h>

#define B_SZ 4
#define T_LEN 8192
#define C_IN 7
#define NPATCH 1023
#define DIM 512
#define NH 8
#define HD 64
#define NLAYERS 4
#define MLP_HID 2048
#define M_ROWS (B_SZ * NPATCH)   // 4092
#define KEMB 128                 // padded patch length (112 real + 16 zero)
#define LN_EPS 1e-5f

typedef __attribute__((ext_vector_type(8))) short short8;
typedef __attribute__((ext_vector_type(4))) float float4v;

static __device__ __forceinline__ unsigned short f2bf(float f) {
  __hip_bfloat16 h = __float2bfloat16(f);
  return *reinterpret_cast<unsigned short*>(&h);
}

// async global->LDS DMA, 16B per lane (wave-uniform LDS base + lane*16)
static __device__ __forceinline__ void gload_lds16(const void* g, void* l) {
  __builtin_amdgcn_global_load_lds(
      (const __attribute__((address_space(1))) unsigned int*)g,
      (__attribute__((address_space(3))) unsigned int*)l, 16, 0, 0);
}

// ---------------------------------------------------------------------------
// Fused preprocessing mega-kernel: 4x weight cvt/transpose + patch gather +
// W_emb cvt + RoPE table, dispatched by blockIdx range. Saves 6 launch gaps.
// ---------------------------------------------------------------------------
#define PB0 3072    // wcvt qkv   (nx=48, ny=16, L=4)
#define PB1 4096    // wcvt proj  (nx=16, ny=16)
#define PB2 8192    // wcvt mlp1  (nx=64, ny=16)
#define PB3 12288   // wcvt mlp2  (nx=16, ny=64)
#define PB4 14334   // patch (2046 blocks)
#define PB5 14590   // wemb (256 blocks)
#define PB6 14718   // rope (128 blocks)

__global__ __launch_bounds__(256) void prep_kernel(
    const float* __restrict__ W_qkv, unsigned short* __restrict__ wqkv_t,
    const float* __restrict__ W_proj, unsigned short* __restrict__ wproj_t,
    const float* __restrict__ W_mlp1, unsigned short* __restrict__ wmlp1_t,
    const float* __restrict__ W_mlp2, unsigned short* __restrict__ wmlp2_t,
    const float* __restrict__ x, unsigned short* __restrict__ Pm,
    const float* __restrict__ W_emb, unsigned short* __restrict__ Wembt,
    float2* __restrict__ rtab) {
  __shared__ float tile[32][33];
  const int bid = blockIdx.x, tid = threadIdx.x;

  auto do_wcvt = [&](const float* W, unsigned short* Wt, int K, int N,
                     int t, int nx, int ny) {
    int xb = t % nx, yb = (t / nx) % ny, L = t / (nx * ny);
    int n0 = xb * 32, k0 = yb * 32;
    const float* Ws = W + (size_t)L * K * N;
    unsigned short* Wd = Wt + (size_t)L * K * N;
    int tx = tid & 31, ty = tid >> 5;
    #pragma unroll
    for (int i = 0; i < 4; ++i)
      tile[ty + i * 8][tx] = Ws[(size_t)(k0 + ty + i * 8) * N + n0 + tx];
    __syncthreads();
    #pragma unroll
    for (int i = 0; i < 4; ++i)
      Wd[(size_t)(n0 + ty + i * 8) * K + k0 + tx] = f2bf(tile[tx][ty + i * 8]);
  };

  if (bid < PB0) {
    do_wcvt(W_qkv, wqkv_t, DIM, 3 * DIM, bid, 48, 16);
  } else if (bid < PB1) {
    do_wcvt(W_proj, wproj_t, DIM, DIM, bid - PB0, 16, 16);
  } else if (bid < PB2) {
    do_wcvt(W_mlp1, wmlp1_t, DIM, MLP_HID, bid - PB1, 64, 16);
  } else if (bid < PB3) {
    do_wcvt(W_mlp2, wmlp2_t, MLP_HID, DIM, bid - PB2, 16, 64);
  } else if (bid < PB4) {
    int idx = (bid - PB3) * 256 + tid;
    if (idx < M_ROWS * KEMB) {
      int row = idx >> 7, c = idx & 127;
      float v = 0.f;
      if (c < 112) {
        int b = row / NPATCH, i = row - b * NPATCH;
        int ci = c >> 4, p = c & 15;
        v = x[((size_t)b * T_LEN + (size_t)i * 8 + p) * C_IN + ci];
      }
      Pm[idx] = f2bf(v);
    }
  } else if (bid < PB5) {
    int idx = (bid - PB4) * 256 + tid;
    if (idx < DIM * KEMB) {
      int n = idx >> 7, k = idx & 127;
      float v = (k < 112) ? W_emb[(size_t)k * DIM + n] : 0.f;
      Wembt[idx] = f2bf(v);
    }
  } else {
    int idx = (bid - PB5) * 256 + tid;
    if (idx < NPATCH * 32) {
      int i = idx >> 5, j = idx & 31;
      float inv = powf(10000.0f, -(float)j * (1.0f / 32.0f));
      float sn, cs;
      sincosf((float)i * inv, &sn, &cs);
      rtab[idx] = make_float2(cs, sn);
    }
  }
}

// ---------------------------------------------------------------------------
// LayerNorm, 4 rows/block. BF: bf16 vs fp32 out.
// ---------------------------------------------------------------------------
template <bool BF>
__global__ __launch_bounds__(256) void ln_kernel(
    const float* __restrict__ in, const float* __restrict__ g,
    const float* __restrict__ bb, void* __restrict__ outv, int M) {
  int row = blockIdx.x * 4 + (threadIdx.x >> 6);
  if (row >= M) return;
  int lane = threadIdx.x & 63;
  const float* xr = in + (size_t)row * DIM;
  float v[8];
  float s = 0.f;
  #pragma unroll
  for (int k = 0; k < 8; ++k) { v[k] = xr[lane + 64 * k]; s += v[k]; }
  #pragma unroll
  for (int off = 32; off; off >>= 1) s += __shfl_down(s, off);
  s = __shfl(s, 0);
  float mu = s * (1.f / DIM);
  float q = 0.f;
  #pragma unroll
  for (int k = 0; k < 8; ++k) { float d = v[k] - mu; q = fmaf(d, d, q); }
  #pragma unroll
  for (int off = 32; off; off >>= 1) q += __shfl_down(q, off);
  q = __shfl(q, 0);
  float rstd = rsqrtf(q * (1.f / DIM) + LN_EPS);
  #pragma unroll
  for (int k = 0; k < 8; ++k) {
    int d = lane + 64 * k;
    float r = (v[k] - mu) * rstd * g[d] + bb[d];
    if (BF)
      ((unsigned short*)outv)[(size_t)row * DIM + d] = f2bf(r);
    else
      ((float*)outv)[(size_t)row * DIM + d] = r;
  }
}

// ---------------------------------------------------------------------------
// bf16 MFMA GEMM v3: global_load_lds staging, templated KSTEP (32 or 64).
//  - LDS linear [2][T][KSTEP]; both-sides 16B-chunk XOR swizzle:
//      KSTEP=32: chunk c at slot c ^ ((row>>1)&3), read quad ^ ((l16>>1)&3)
//      KSTEP=64: chunk c at slot c ^ (row&7),      read (t*4+quad) ^ (l16&7)
//    ds_read_b128 conflicts: 2-way (free).
//  - One barrier per KSTEP; DMA for next tile issued right after barrier,
//    flies across ds_read + MFMA, drained by the next barrier.
//  - A rows NOT predicated (DMA can't): OOB rows read mapped ws slack,
//    garbage only reaches acc rows never stored.
// EPI: 1 = bias+res -> fp32; 2 = bias+GELU -> bf16; 3 = bias -> bf16;
//      5 = bias -> fp32 to Cf and Cf2 (embed); 6 = bias+RoPE -> bf16 (WN=64).
// ---------------------------------------------------------------------------
template <int TM, int TN, int KSTEP, int EPI>
__global__ __launch_bounds__(256) void mfma_gemm(
    const unsigned short* __restrict__ A, const unsigned short* __restrict__ Bt,
    const float* __restrict__ bias, const float* __restrict__ res,
    float* __restrict__ Cf, float* __restrict__ Cf2,
    unsigned short* __restrict__ Cb, const float2* __restrict__ rtab,
    int M, int N, int K) {
  constexpr int WM = TM / 2, WN = TN / 2;
  constexpr int NI = WM / 16, NJ = WN / 16;
  constexpr int RCH = KSTEP / 8;            // 16B chunks per row (4 or 8)
  constexpr int RPU = 64 / RCH;             // rows per 1KB DMA unit (16 or 8)
  constexpr int AU = TM / RPU;              // A units
  constexpr int NU = (TM + TN) / RPU;       // total units
  constexpr int CPW = NU / 4;               // units per wave
  constexpr int SH = (KSTEP == 32) ? 1 : 0; // row swizzle shift
  __shared__ __align__(16) unsigned short As[2][TM][KSTEP];
  __shared__ __align__(16) unsigned short Bs[2][TN][KSTEP];
  const int bm = blockIdx.y * TM;
  const int bn = blockIdx.x * TN;
  const int tid = threadIdx.x;
  const int lane = tid & 63, wave = tid >> 6;
  const int quad = lane >> 4, l16 = lane & 15;
  const int wm = (wave & 1) * WM;
  const int wn = (wave >> 1) * WN;
  const int lrow = lane / RCH, lc = lane & (RCH - 1);   // DMA src decomp
  const int rsw = (l16 >> SH) & (RCH - 1);              // read swizzle

  float4v acc[NI][NJ];
  #pragma unroll
  for (int i = 0; i < NI; ++i)
    #pragma unroll
    for (int j = 0; j < NJ; ++j)
      acc[i][j] = (float4v){0.f, 0.f, 0.f, 0.f};

  auto stage = [&](int bufI, int kk) {
    #pragma unroll
    for (int it = 0; it < CPW; ++it) {
      int u = wave * CPW + it;
      if (u < AU) {
        int row = u * RPU + lrow;
        int col16 = lc ^ ((row >> SH) & (RCH - 1));
        gload_lds16(A + (size_t)(bm + row) * K + kk + col16 * 8,
                    &As[bufI][u * RPU][0]);
      } else {
        int row = (u - AU) * RPU + lrow;
        int col16 = lc ^ ((row >> SH) & (RCH - 1));
        gload_lds16(Bt + (size_t)(bn + row) * K + kk + col16 * 8,
                    &Bs[bufI][(u - AU) * RPU][0]);
      }
    }
  };

  stage(0, 0);
  int buf = 0;
  for (int k0 = 0; k0 < K; k0 += KSTEP, buf ^= 1) {
    __syncthreads();   // drains own DMA + barrier: tile visible, other buf free
    if (k0 + KSTEP < K) stage(buf ^ 1, k0 + KSTEP);  // flies across MFMA
    #pragma unroll
    for (int t = 0; t < KSTEP / 32; ++t) {
      short8 af[NI], bfr[NJ];
      #pragma unroll
      for (int i = 0; i < NI; ++i) {
        int rslot = (t * 4 + quad) ^ rsw;
        af[i] = *(const short8*)&As[buf][wm + i * 16 + l16][rslot * 8];
      }
      #pragma unroll
      for (int j = 0; j < NJ; ++j) {
        int rslot = (t * 4 + quad) ^ rsw;
        bfr[j] = *(const short8*)&Bs[buf][wn + j * 16 + l16][rslot * 8];
      }
      __builtin_amdgcn_s_setprio(1);
      #pragma unroll
      for (int i = 0; i < NI; ++i)
        #pragma unroll
        for (int j = 0; j < NJ; ++j)
          acc[i][j] = __builtin_amdgcn_mfma_f32_16x16x32_bf16(
              af[i], bfr[j], acc[i][j], 0, 0, 0);
      __builtin_amdgcn_s_setprio(0);
    }
  }

  if (EPI == 6) {
    const int sec = (bn + wn) >> 9;   // 0=q, 1=k, 2=v (wave-uniform; WN=64)
    #pragma unroll
    for (int i = 0; i < NI; ++i) {
      int gm0 = bm + wm + i * 16 + quad * 4;
      #pragma unroll
      for (int r = 0; r < 4; ++r) {
        int gm = gm0 + r;
        if (gm >= M) continue;
        size_t rowoff = (size_t)gm * N;
        if (sec < 2) {
          int ip = gm; if (ip >= 2046) ip -= 2046; if (ip >= 1023) ip -= 1023;
          float sc = (sec == 0) ? 0.125f : 1.f;
          #pragma unroll
          for (int j = 0; j < NJ / 2; ++j) {
            int gn = bn + wn + j * 16 + l16;
            float v0 = acc[i][j][r] + bias[gn];
            float v1 = acc[i][j + NJ / 2][r] + bias[gn + 32];
            float2 t = rtab[ip * 32 + j * 16 + l16];
            Cb[rowoff + gn]      = f2bf((v0 * t.x - v1 * t.y) * sc);
            Cb[rowoff + gn + 32] = f2bf((v1 * t.x + v0 * t.y) * sc);
          }
        } else {
          #pragma unroll
          for (int j = 0; j < NJ; ++j) {
            int gn = bn + wn + j * 16 + l16;
            Cb[rowoff + gn] = f2bf(acc[i][j][r] + bias[gn]);
          }
        }
      }
    }
    return;
  }

  #pragma unroll
  for (int j = 0; j < NJ; ++j) {
    int gn = bn + wn + j * 16 + l16;
    float bv = bias[gn];
    #pragma unroll
    for (int i = 0; i < NI; ++i) {
      int gm0 = bm + wm + i * 16 + quad * 4;
      #pragma unroll
      for (int r = 0; r < 4; ++r) {
        int gm = gm0 + r;
        if (gm < M) {
          float v = acc[i][j][r] + bv;
          size_t off = (size_t)gm * N + gn;
          if (EPI == 1) {
            Cf[off] = v + res[off];
          } else if (EPI == 2) {
            Cb[off] = f2bf(0.5f * v * (1.f + erff(v * 0.70710678118f)));
          } else if (EPI == 3) {
            Cb[off] = f2bf(v);
          } else {
            Cf[off] = v;
            Cf2[off] = v;
          }
        }
      }
    }
  }
}

// ---------------------------------------------------------------------------
// MFMA flash attention v5 (unchanged from R5): IN-BLOCK split-K, 8 waves.
// ---------------------------------------------------------------------------
#define APITCH 72

__global__ __launch_bounds__(512, 4) void attn_kernel(
    const unsigned short* __restrict__ qkvb, unsigned short* __restrict__ o) {
  const int bid = blockIdx.x;
  const int xcd = bid & 7, slot = bid >> 3;
  const int qt0 = (slot & 15) * 64;
  const int gh = xcd + 8 * (slot >> 4);    // 0..31
  const int h = gh & 7, b = gh >> 3;

  const int tid = threadIdx.x;
  const int lane = tid & 63, wave = tid >> 6;
  const int quad = lane >> 4, l16 = lane & 15;
  const int half = wave >> 2, wq = wave & 3;

  __shared__ __align__(16) unsigned short Ks[2][64][APITCH];  // [half][key][d]
  __shared__ __align__(16) unsigned short Vt[2][64][APITCH];  // [half][d][key]
  __shared__ __align__(16) unsigned short Ps[8][16][APITCH];  // per-wave P; merge buf

  short8 aq0 = {0, 0, 0, 0, 0, 0, 0, 0}, aq1 = aq0;
  {
    int qrow = qt0 + wq * 16 + l16;
    if (qrow < NPATCH) {
      const uint4* qr = (const uint4*)(qkvb + (size_t)(b * NPATCH + qrow) * (3 * DIM) + h * HD + quad * 8);
      aq0 = __builtin_bit_cast(short8, qr[0]);
      aq1 = __builtin_bit_cast(short8, qr[4]);
    }
  }

  const int krow = tid >> 2, kc0 = (tid & 3) * 16;
  const int kp2 = tid & 63, dg = tid >> 6;
  uint4 pk0, pk1, pv0, pv1;
  auto load_kv = [&](int js) {
    pk0 = pk1 = pv0 = pv1 = make_uint4(0u, 0u, 0u, 0u);
    int jk = js + krow;
    if (jk < NPATCH) {
      const unsigned short* kb = qkvb + (size_t)(b * NPATCH + jk) * (3 * DIM) + DIM + h * HD;
      pk0 = *(const uint4*)(kb + kc0);
      pk1 = *(const uint4*)(kb + kc0 + 8);
    }
    int jv = js + 2 * kp2;
    const unsigned short* vb = qkvb + (size_t)(b * NPATCH + jv) * (3 * DIM) + 2 * DIM + h * HD + dg * 8;
    if (jv < NPATCH)     pv0 = *(const uint4*)vb;
    if (jv + 1 < NPATCH) pv1 = *(const uint4*)(vb + 3 * DIM);
  };

  load_kv(0);

  float4v accO[4];
  #pragma unroll
  for (int j2 = 0; j2 < 4; ++j2) accO[j2] = (float4v){0.f, 0.f, 0.f, 0.f};
  float m_run[4] = {-1e30f, -1e30f, -1e30f, -1e30f};
  float lp[4] = {0.f, 0.f, 0.f, 0.f};

  constexpr int NIT = (NPATCH + 127) / 128;   // 8 slabs of 128 keys
  for (int it = 0; it < NIT; ++it) {
    if (it > 0) __syncthreads();
    {
      *(uint4*)&Ks[krow >> 6][krow & 63][kc0] = pk0;
      *(uint4*)&Ks[krow >> 6][krow & 63][kc0 + 8] = pk1;
      unsigned short va[8], vb8[8];
      *(uint4*)&va[0] = pv0;
      *(uint4*)&vb8[0] = pv1;
      const int vh = kp2 >> 5, lp2 = kp2 & 31;
      #pragma unroll
      for (int u = 0; u < 8; ++u) {
        unsigned pk = (unsigned)va[u] | ((unsigned)vb8[u] << 16);
        *(unsigned*)&Vt[vh][dg * 8 + u][2 * lp2] = pk;
      }
    }
    __syncthreads();
    if (it + 1 < NIT) load_kv((it + 1) * 128);

    const int j0 = it * 128 + half * 64;

    float4v s[4];
    __builtin_amdgcn_s_setprio(1);
    #pragma unroll
    for (int j = 0; j < 4; ++j) {
      s[j] = (float4v){0.f, 0.f, 0.f, 0.f};
      short8 bk0 = *(const short8*)&Ks[half][j * 16 + l16][quad * 8];
      short8 bk1 = *(const short8*)&Ks[half][j * 16 + l16][32 + quad * 8];
      s[j] = __builtin_amdgcn_mfma_f32_16x16x32_bf16(aq0, bk0, s[j], 0, 0, 0);
      s[j] = __builtin_amdgcn_mfma_f32_16x16x32_bf16(aq1, bk1, s[j], 0, 0, 0);
    }
    __builtin_amdgcn_s_setprio(0);

    float mx[4];
    #pragma unroll
    for (int r = 0; r < 4; ++r)
      mx[r] = fmaxf(fmaxf(s[0][r], s[1][r]), fmaxf(s[2][r], s[3][r]));
    #pragma unroll
    for (int mask = 1; mask < 16; mask <<= 1)
      #pragma unroll
      for (int r = 0; r < 4; ++r)
        mx[r] = fmaxf(mx[r], __shfl_xor(mx[r], mask));
    float gmax = fmaxf(fmaxf(mx[0] - m_run[0], mx[1] - m_run[1]),
                       fmaxf(mx[2] - m_run[2], mx[3] - m_run[3]));
    if (!__all(gmax <= 8.f)) {
      #pragma unroll
      for (int r = 0; r < 4; ++r) {
        float mnew = fmaxf(m_run[r], mx[r]);
        float al = __expf(m_run[r] - mnew);
        m_run[r] = mnew;
        lp[r] *= al;
        #pragma unroll
        for (int j2 = 0; j2 < 4; ++j2) accO[j2][r] *= al;
      }
    }
    #pragma unroll
    for (int j = 0; j < 4; ++j) {
      bool valid = (j0 + j * 16 + l16) < NPATCH;
      #pragma unroll
      for (int r = 0; r < 4; ++r) {
        float p = valid ? __expf(s[j][r] - m_run[r]) : 0.f;
        lp[r] += p;
        Ps[wave][quad * 4 + r][j * 16 + l16] = f2bf(p);
      }
    }

    short8 pa0 = *(const short8*)&Ps[wave][l16][quad * 8];
    short8 pa1 = *(const short8*)&Ps[wave][l16][32 + quad * 8];
    __builtin_amdgcn_s_setprio(1);
    #pragma unroll
    for (int j2 = 0; j2 < 4; ++j2) {
      short8 v0 = *(const short8*)&Vt[half][j2 * 16 + l16][quad * 8];
      short8 v1 = *(const short8*)&Vt[half][j2 * 16 + l16][32 + quad * 8];
      accO[j2] = __builtin_amdgcn_mfma_f32_16x16x32_bf16(pa0, v0, accO[j2], 0, 0, 0);
      accO[j2] = __builtin_amdgcn_mfma_f32_16x16x32_bf16(pa1, v1, accO[j2], 0, 0, 0);
    }
    __builtin_amdgcn_s_setprio(0);
  }

  #pragma unroll
  for (int mask = 1; mask < 16; mask <<= 1)
    #pragma unroll
    for (int r = 0; r < 4; ++r)
      lp[r] += __shfl_xor(lp[r], mask);

  float* Pf = (float*)&Ps[0][0][0];
  __syncthreads();
  if (half == 1) {
    #pragma unroll
    for (int j2 = 0; j2 < 4; ++j2)
      #pragma unroll
      for (int r = 0; r < 4; ++r)
        Pf[((wq * 64 + lane) << 4) + j2 * 4 + r] = accO[j2][r];
    if (l16 == 0) {
      #pragma unroll
      for (int r = 0; r < 4; ++r) {
        Pf[4096 + ((wq * 16 + quad * 4 + r) << 1)]     = m_run[r];
        Pf[4096 + ((wq * 16 + quad * 4 + r) << 1) + 1] = lp[r];
      }
    }
  }
  __syncthreads();
  if (half == 0) {
    #pragma unroll
    for (int r = 0; r < 4; ++r) {
      float m1 = Pf[4096 + ((wq * 16 + quad * 4 + r) << 1)];
      float l1 = Pf[4096 + ((wq * 16 + quad * 4 + r) << 1) + 1];
      float M = fmaxf(m_run[r], m1);
      float w0 = __expf(m_run[r] - M), w1 = __expf(m1 - M);
      float inv = 1.f / (w0 * lp[r] + w1 * l1);
      int qi = qt0 + wq * 16 + quad * 4 + r;
      if (qi < NPATCH) {
        size_t off = (size_t)(b * NPATCH + qi) * DIM + h * HD + l16;
        #pragma unroll
        for (int j2 = 0; j2 < 4; ++j2) {
          float a1 = Pf[((wq * 64 + lane) << 4) + j2 * 4 + r];
          o[off + j2 * 16] = f2bf((w0 * accO[j2][r] + w1 * a1) * inv);
        }
      }
    }
  }
}

// ---------------------------------------------------------------------------
extern "C" void kernel_launch(void* const* d_in, const int* in_sizes, int n_in,
                              void* d_out, int out_size, void* d_ws, size_t ws_size,
                              hipStream_t stream) {
  const float* x      = (const float*)d_in[0];
  const float* W_emb  = (const float*)d_in[1];
  const float* b_emb  = (const float*)d_in[2];
  const float* ln1_g  = (const float*)d_in[3];
  const float* ln1_b  = (const float*)d_in[4];
  const float* W_qkv  = (const float*)d_in[5];
  const float* b_qkv  = (const float*)d_in[6];
  const float* W_proj = (const float*)d_in[7];
  const float* b_proj = (const float*)d_in[8];
  const float* ln2_g  = (const float*)d_in[9];
  const float* ln2_b  = (const float*)d_in[10];
  const float* W_mlp1 = (const float*)d_in[11];
  const float* b_mlp1 = (const float*)d_in[12];
  const float* W_mlp2 = (const float*)d_in[13];
  const float* b_mlp2 = (const float*)d_in[14];
  const float* lnf_g  = (const float*)d_in[15];
  const float* lnf_b  = (const float*)d_in[16];
  float* out = (float*)d_out;

  float* h              = (float*)d_ws;
  unsigned short* qkvb  = (unsigned short*)(h + (size_t)M_ROWS * DIM);
  unsigned short* midbf = qkvb;   // alias: qkvb dead after attn
  unsigned short* ybf   = qkvb + (size_t)M_ROWS * MLP_HID;
  unsigned short* obf   = ybf;    // alias: ybf dead after its GEMM
  unsigned short* wqkv_t  = ybf + (size_t)M_ROWS * DIM;
  unsigned short* wproj_t = wqkv_t  + (size_t)NLAYERS * DIM * 3 * DIM;
  unsigned short* wmlp1_t = wproj_t + (size_t)NLAYERS * DIM * DIM;
  unsigned short* wmlp2_t = wmlp1_t + (size_t)NLAYERS * DIM * MLP_HID;
  float2* rtab = (float2*)(wmlp2_t + (size_t)NLAYERS * MLP_HID * DIM);
  unsigned short* Pm    = (unsigned short*)(rtab + (size_t)NPATCH * 32);
  unsigned short* Wembt = Pm + (size_t)M_ROWS * KEMB;

  prep_kernel<<<dim3(PB6), 256, 0, stream>>>(
      W_qkv, wqkv_t, W_proj, wproj_t, W_mlp1, wmlp1_t, W_mlp2, wmlp2_t,
      x, Pm, W_emb, Wembt, rtab);

  const int MT64 = (M_ROWS + 63) / 64;     // 64
  const int MT128 = (M_ROWS + 127) / 128;  // 32
  const int LNG = (M_ROWS + 3) / 4;        // 1023

  // embed: out & h = Pm @ Wembt^T + b_emb  (64x64, BK=64: 2 iters)
  mfma_gemm<64, 64, 64, 5><<<dim3(DIM / 64, MT64), 256, 0, stream>>>(
      Pm, Wembt, b_emb, nullptr, out, h, nullptr, nullptr, M_ROWS, DIM, KEMB);

  for (int L = 0; L < NLAYERS; ++L) {
    ln_kernel<true><<<LNG, 256, 0, stream>>>(h, ln1_g + L * DIM, ln1_b + L * DIM, ybf, M_ROWS);
    // qkv with fused RoPE (64x128 tiles: 12x64 = 768 blocks, 3/CU)
    mfma_gemm<64, 128, 32, 6><<<dim3(3 * DIM / 128, MT64), 256, 0, stream>>>(
        ybf, wqkv_t + (size_t)L * DIM * 3 * DIM, b_qkv + L * 3 * DIM,
        nullptr, nullptr, nullptr, qkvb, rtab, M_ROWS, 3 * DIM, DIM);
    attn_kernel<<<dim3(512), 512, 0, stream>>>(qkvb, obf);
    // proj: h += o @ Wp + bias  (64x64, BK=64: 8 iters)
    mfma_gemm<64, 64, 64, 1><<<dim3(DIM / 64, MT64), 256, 0, stream>>>(
        obf, wproj_t + (size_t)L * DIM * DIM, b_proj + L * DIM,
        h, h, nullptr, nullptr, nullptr, M_ROWS, DIM, DIM);
    ln_kernel<true><<<LNG, 256, 0, stream>>>(h, ln2_g + L * DIM, ln2_b + L * DIM, ybf, M_ROWS);
    // mlp1 + GELU (128x128, BK=32: proven R5 config)
    mfma_gemm<128, 128, 32, 2><<<dim3(MLP_HID / 128, MT128), 256, 0, stream>>>(
        ybf, wmlp1_t + (size_t)L * DIM * MLP_HID, b_mlp1 + L * MLP_HID,
        nullptr, nullptr, nullptr, midbf, nullptr, M_ROWS, MLP_HID, DIM);
    // mlp2: h += mid @ Wm2 + bias  (64x64, BK=64: 32 iters vs 64)
    mfma_gemm<64, 64, 64, 1><<<dim3(DIM / 64, MT64), 256, 0, stream>>>(
        midbf, wmlp2_t + (size_t)L * MLP_HID * DIM, b_mlp2 + L * DIM,
        h, h, nullptr, nullptr, nullptr, M_ROWS, DIM, MLP_HID);
  }

  ln_kernel<false><<<LNG, 256, 0, stream>>>(h, lnf_g, lnf_b, out + (size_t)M_ROWS * DIM, M_ROWS);
}

// Round 7
// 582.197 us; speedup vs baseline: 1.3141x; 1.0517x over previous
//
#include <hip/hip_runtime.h>
#include <hip/hip_bf16.h>
#include <math.h>

#define B_SZ 4
#define T_LEN 8192
#define C_IN 7
#define NPATCH 1023
#define DIM 512
#define NH 8
#define HD 64
#define NLAYERS 4
#define MLP_HID 2048
#define M_ROWS (B_SZ * NPATCH)   // 4092
#define KEMB 128                 // padded patch length (112 real + 16 zero)
#define LN_EPS 1e-5f

typedef __attribute__((ext_vector_type(8))) short short8;
typedef __attribute__((ext_vector_type(4))) float float4v;

static __device__ __forceinline__ unsigned short f2bf(float f) {
  __hip_bfloat16 h = __float2bfloat16(f);
  return *reinterpret_cast<unsigned short*>(&h);
}

// async global->LDS DMA, 16B per lane (wave-uniform LDS base + lane*16)
static __device__ __forceinline__ void gload_lds16(const void* g, void* l) {
  __builtin_amdgcn_global_load_lds(
      (const __attribute__((address_space(1))) unsigned int*)g,
      (__attribute__((address_space(3))) unsigned int*)l, 16, 0, 0);
}

// ---------------------------------------------------------------------------
// Fused preprocessing mega-kernel (unchanged from R6).
// ---------------------------------------------------------------------------
#define PB0 3072    // wcvt qkv   (nx=48, ny=16, L=4)
#define PB1 4096    // wcvt proj  (nx=16, ny=16)
#define PB2 8192    // wcvt mlp1  (nx=64, ny=16)
#define PB3 12288   // wcvt mlp2  (nx=16, ny=64)
#define PB4 14334   // patch (2046 blocks)
#define PB5 14590   // wemb (256 blocks)
#define PB6 14718   // rope (128 blocks)

__global__ __launch_bounds__(256) void prep_kernel(
    const float* __restrict__ W_qkv, unsigned short* __restrict__ wqkv_t,
    const float* __restrict__ W_proj, unsigned short* __restrict__ wproj_t,
    const float* __restrict__ W_mlp1, unsigned short* __restrict__ wmlp1_t,
    const float* __restrict__ W_mlp2, unsigned short* __restrict__ wmlp2_t,
    const float* __restrict__ x, unsigned short* __restrict__ Pm,
    const float* __restrict__ W_emb, unsigned short* __restrict__ Wembt,
    float2* __restrict__ rtab) {
  __shared__ float tile[32][33];
  const int bid = blockIdx.x, tid = threadIdx.x;

  auto do_wcvt = [&](const float* W, unsigned short* Wt, int K, int N,
                     int t, int nx, int ny) {
    int xb = t % nx, yb = (t / nx) % ny, L = t / (nx * ny);
    int n0 = xb * 32, k0 = yb * 32;
    const float* Ws = W + (size_t)L * K * N;
    unsigned short* Wd = Wt + (size_t)L * K * N;
    int tx = tid & 31, ty = tid >> 5;
    #pragma unroll
    for (int i = 0; i < 4; ++i)
      tile[ty + i * 8][tx] = Ws[(size_t)(k0 + ty + i * 8) * N + n0 + tx];
    __syncthreads();
    #pragma unroll
    for (int i = 0; i < 4; ++i)
      Wd[(size_t)(n0 + ty + i * 8) * K + k0 + tx] = f2bf(tile[tx][ty + i * 8]);
  };

  if (bid < PB0) {
    do_wcvt(W_qkv, wqkv_t, DIM, 3 * DIM, bid, 48, 16);
  } else if (bid < PB1) {
    do_wcvt(W_proj, wproj_t, DIM, DIM, bid - PB0, 16, 16);
  } else if (bid < PB2) {
    do_wcvt(W_mlp1, wmlp1_t, DIM, MLP_HID, bid - PB1, 64, 16);
  } else if (bid < PB3) {
    do_wcvt(W_mlp2, wmlp2_t, MLP_HID, DIM, bid - PB2, 16, 64);
  } else if (bid < PB4) {
    int idx = (bid - PB3) * 256 + tid;
    if (idx < M_ROWS * KEMB) {
      int row = idx >> 7, c = idx & 127;
      float v = 0.f;
      if (c < 112) {
        int b = row / NPATCH, i = row - b * NPATCH;
        int ci = c >> 4, p = c & 15;
        v = x[((size_t)b * T_LEN + (size_t)i * 8 + p) * C_IN + ci];
      }
      Pm[idx] = f2bf(v);
    }
  } else if (bid < PB5) {
    int idx = (bid - PB4) * 256 + tid;
    if (idx < DIM * KEMB) {
      int n = idx >> 7, k = idx & 127;
      float v = (k < 112) ? W_emb[(size_t)k * DIM + n] : 0.f;
      Wembt[idx] = f2bf(v);
    }
  } else {
    int idx = (bid - PB5) * 256 + tid;
    if (idx < NPATCH * 32) {
      int i = idx >> 5, j = idx & 31;
      float inv = powf(10000.0f, -(float)j * (1.0f / 32.0f));
      float sn, cs;
      sincosf((float)i * inv, &sn, &cs);
      rtab[idx] = make_float2(cs, sn);
    }
  }
}

// ---------------------------------------------------------------------------
// LayerNorm, 4 rows/block. BF: bf16 vs fp32 out.
// ---------------------------------------------------------------------------
template <bool BF>
__global__ __launch_bounds__(256) void ln_kernel(
    const float* __restrict__ in, const float* __restrict__ g,
    const float* __restrict__ bb, void* __restrict__ outv, int M) {
  int row = blockIdx.x * 4 + (threadIdx.x >> 6);
  if (row >= M) return;
  int lane = threadIdx.x & 63;
  const float* xr = in + (size_t)row * DIM;
  float v[8];
  float s = 0.f;
  #pragma unroll
  for (int k = 0; k < 8; ++k) { v[k] = xr[lane + 64 * k]; s += v[k]; }
  #pragma unroll
  for (int off = 32; off; off >>= 1) s += __shfl_down(s, off);
  s = __shfl(s, 0);
  float mu = s * (1.f / DIM);
  float q = 0.f;
  #pragma unroll
  for (int k = 0; k < 8; ++k) { float d = v[k] - mu; q = fmaf(d, d, q); }
  #pragma unroll
  for (int off = 32; off; off >>= 1) q += __shfl_down(q, off);
  q = __shfl(q, 0);
  float rstd = rsqrtf(q * (1.f / DIM) + LN_EPS);
  #pragma unroll
  for (int k = 0; k < 8; ++k) {
    int d = lane + 64 * k;
    float r = (v[k] - mu) * rstd * g[d] + bb[d];
    if (BF)
      ((unsigned short*)outv)[(size_t)row * DIM + d] = f2bf(r);
    else
      ((float*)outv)[(size_t)row * DIM + d] = r;
  }
}

// ---------------------------------------------------------------------------
// bf16 MFMA GEMM v4: DMA staging + XCD-aware 1-D grid swizzle.
//  - Grid is 1-D (nwg = nx*ny, nwg % 8 == 0). Decode:
//      wg = (bid & 7) * (nwg/8) + (bid >> 3);  bx = wg % nx;  by = wg / nx
//    Each XCD gets a contiguous by-major chunk -> its A-strips + B panels
//    stay L2-resident (per-XCD working set <= 4 MB for all our shapes).
//  - LDS linear [2][T][KSTEP]; both-sides 16B-chunk XOR swizzle (R5/R6).
//  - One barrier per KSTEP; next-tile DMA issued after barrier, flies
//    across ds_read + MFMA, drained by the next barrier.
//  - A rows NOT predicated (DMA can't): OOB rows read mapped ws slack.
// EPI: 1 = bias+res -> fp32; 2 = bias+GELU -> bf16; 3 = bias -> bf16;
//      5 = bias -> fp32 to Cf and Cf2 (embed); 6 = bias+RoPE -> bf16 (WN=64,
//          q scaled by 0.125*log2e for exp2 softmax downstream).
// ---------------------------------------------------------------------------
template <int TM, int TN, int KSTEP, int EPI>
__global__ __launch_bounds__(256) void mfma_gemm(
    const unsigned short* __restrict__ A, const unsigned short* __restrict__ Bt,
    const float* __restrict__ bias, const float* __restrict__ res,
    float* __restrict__ Cf, float* __restrict__ Cf2,
    unsigned short* __restrict__ Cb, const float2* __restrict__ rtab,
    int M, int N, int K) {
  constexpr int WM = TM / 2, WN = TN / 2;
  constexpr int NI = WM / 16, NJ = WN / 16;
  constexpr int RCH = KSTEP / 8;            // 16B chunks per row (4 or 8)
  constexpr int RPU = 64 / RCH;             // rows per 1KB DMA unit (16 or 8)
  constexpr int AU = TM / RPU;              // A units
  constexpr int NU = (TM + TN) / RPU;       // total units
  constexpr int CPW = NU / 4;               // units per wave
  constexpr int SH = (KSTEP == 32) ? 1 : 0; // row swizzle shift
  __shared__ __align__(16) unsigned short As[2][TM][KSTEP];
  __shared__ __align__(16) unsigned short Bs[2][TN][KSTEP];
  // XCD-aware decode (nwg % 8 == 0 guaranteed by launch config)
  const int nwg = gridDim.x;
  const int nx = N / TN;
  const int wg = (blockIdx.x & 7) * (nwg >> 3) + (blockIdx.x >> 3);
  const int bm = (wg / nx) * TM;
  const int bn = (wg % nx) * TN;
  const int tid = threadIdx.x;
  const int lane = tid & 63, wave = tid >> 6;
  const int quad = lane >> 4, l16 = lane & 15;
  const int wm = (wave & 1) * WM;
  const int wn = (wave >> 1) * WN;
  const int lrow = lane / RCH, lc = lane & (RCH - 1);   // DMA src decomp
  const int rsw = (l16 >> SH) & (RCH - 1);              // read swizzle

  float4v acc[NI][NJ];
  #pragma unroll
  for (int i = 0; i < NI; ++i)
    #pragma unroll
    for (int j = 0; j < NJ; ++j)
      acc[i][j] = (float4v){0.f, 0.f, 0.f, 0.f};

  auto stage = [&](int bufI, int kk) {
    #pragma unroll
    for (int it = 0; it < CPW; ++it) {
      int u = wave * CPW + it;
      if (u < AU) {
        int row = u * RPU + lrow;
        int col16 = lc ^ ((row >> SH) & (RCH - 1));
        gload_lds16(A + (size_t)(bm + row) * K + kk + col16 * 8,
                    &As[bufI][u * RPU][0]);
      } else {
        int row = (u - AU) * RPU + lrow;
        int col16 = lc ^ ((row >> SH) & (RCH - 1));
        gload_lds16(Bt + (size_t)(bn + row) * K + kk + col16 * 8,
                    &Bs[bufI][(u - AU) * RPU][0]);
      }
    }
  };

  stage(0, 0);
  int buf = 0;
  for (int k0 = 0; k0 < K; k0 += KSTEP, buf ^= 1) {
    __syncthreads();   // drains own DMA + barrier: tile visible, other buf free
    if (k0 + KSTEP < K) stage(buf ^ 1, k0 + KSTEP);  // flies across MFMA
    #pragma unroll
    for (int t = 0; t < KSTEP / 32; ++t) {
      short8 af[NI], bfr[NJ];
      #pragma unroll
      for (int i = 0; i < NI; ++i) {
        int rslot = (t * 4 + quad) ^ rsw;
        af[i] = *(const short8*)&As[buf][wm + i * 16 + l16][rslot * 8];
      }
      #pragma unroll
      for (int j = 0; j < NJ; ++j) {
        int rslot = (t * 4 + quad) ^ rsw;
        bfr[j] = *(const short8*)&Bs[buf][wn + j * 16 + l16][rslot * 8];
      }
      __builtin_amdgcn_s_setprio(1);
      #pragma unroll
      for (int i = 0; i < NI; ++i)
        #pragma unroll
        for (int j = 0; j < NJ; ++j)
          acc[i][j] = __builtin_amdgcn_mfma_f32_16x16x32_bf16(
              af[i], bfr[j], acc[i][j], 0, 0, 0);
      __builtin_amdgcn_s_setprio(0);
    }
  }

  if (EPI == 6) {
    const int sec = (bn + wn) >> 9;   // 0=q, 1=k, 2=v (wave-uniform; WN=64)
    #pragma unroll
    for (int i = 0; i < NI; ++i) {
      int gm0 = bm + wm + i * 16 + quad * 4;
      #pragma unroll
      for (int r = 0; r < 4; ++r) {
        int gm = gm0 + r;
        if (gm >= M) continue;
        size_t rowoff = (size_t)gm * N;
        if (sec < 2) {
          int ip = gm; if (ip >= 2046) ip -= 2046; if (ip >= 1023) ip -= 1023;
          // q pre-scaled by log2e so attn can use exp2 directly
          float sc = (sec == 0) ? 0.125f * 1.44269504f : 1.f;
          #pragma unroll
          for (int j = 0; j < NJ / 2; ++j) {
            int gn = bn + wn + j * 16 + l16;
            float v0 = acc[i][j][r] + bias[gn];
            float v1 = acc[i][j + NJ / 2][r] + bias[gn + 32];
            float2 t = rtab[ip * 32 + j * 16 + l16];
            Cb[rowoff + gn]      = f2bf((v0 * t.x - v1 * t.y) * sc);
            Cb[rowoff + gn + 32] = f2bf((v1 * t.x + v0 * t.y) * sc);
          }
        } else {
          #pragma unroll
          for (int j = 0; j < NJ; ++j) {
            int gn = bn + wn + j * 16 + l16;
            Cb[rowoff + gn] = f2bf(acc[i][j][r] + bias[gn]);
          }
        }
      }
    }
    return;
  }

  #pragma unroll
  for (int j = 0; j < NJ; ++j) {
    int gn = bn + wn + j * 16 + l16;
    float bv = bias[gn];
    #pragma unroll
    for (int i = 0; i < NI; ++i) {
      int gm0 = bm + wm + i * 16 + quad * 4;
      #pragma unroll
      for (int r = 0; r < 4; ++r) {
        int gm = gm0 + r;
        if (gm < M) {
          float v = acc[i][j][r] + bv;
          size_t off = (size_t)gm * N + gn;
          if (EPI == 1) {
            Cf[off] = v + res[off];
          } else if (EPI == 2) {
            Cb[off] = f2bf(0.5f * v * (1.f + erff(v * 0.70710678118f)));
          } else if (EPI == 3) {
            Cb[off] = f2bf(v);
          } else {
            Cf[off] = v;
            Cf2[off] = v;
          }
        }
      }
    }
  }
}

// ---------------------------------------------------------------------------
// MFMA flash attention v5.1: v5 structure + exp2 softmax (q pre-scaled by
// log2e in the qkv epilogue; exp2f == v_exp_f32 directly). Same math.
// ---------------------------------------------------------------------------
#define APITCH 72

__global__ __launch_bounds__(512, 4) void attn_kernel(
    const unsigned short* __restrict__ qkvb, unsigned short* __restrict__ o) {
  const int bid = blockIdx.x;
  const int xcd = bid & 7, slot = bid >> 3;
  const int qt0 = (slot & 15) * 64;
  const int gh = xcd + 8 * (slot >> 4);    // 0..31
  const int h = gh & 7, b = gh >> 3;

  const int tid = threadIdx.x;
  const int lane = tid & 63, wave = tid >> 6;
  const int quad = lane >> 4, l16 = lane & 15;
  const int half = wave >> 2, wq = wave & 3;

  __shared__ __align__(16) unsigned short Ks[2][64][APITCH];  // [half][key][d]
  __shared__ __align__(16) unsigned short Vt[2][64][APITCH];  // [half][d][key]
  __shared__ __align__(16) unsigned short Ps[8][16][APITCH];  // per-wave P; merge buf

  short8 aq0 = {0, 0, 0, 0, 0, 0, 0, 0}, aq1 = aq0;
  {
    int qrow = qt0 + wq * 16 + l16;
    if (qrow < NPATCH) {
      const uint4* qr = (const uint4*)(qkvb + (size_t)(b * NPATCH + qrow) * (3 * DIM) + h * HD + quad * 8);
      aq0 = __builtin_bit_cast(short8, qr[0]);
      aq1 = __builtin_bit_cast(short8, qr[4]);
    }
  }

  const int krow = tid >> 2, kc0 = (tid & 3) * 16;
  const int kp2 = tid & 63, dg = tid >> 6;
  uint4 pk0, pk1, pv0, pv1;
  auto load_kv = [&](int js) {
    pk0 = pk1 = pv0 = pv1 = make_uint4(0u, 0u, 0u, 0u);
    int jk = js + krow;
    if (jk < NPATCH) {
      const unsigned short* kb = qkvb + (size_t)(b * NPATCH + jk) * (3 * DIM) + DIM + h * HD;
      pk0 = *(const uint4*)(kb + kc0);
      pk1 = *(const uint4*)(kb + kc0 + 8);
    }
    int jv = js + 2 * kp2;
    const unsigned short* vb = qkvb + (size_t)(b * NPATCH + jv) * (3 * DIM) + 2 * DIM + h * HD + dg * 8;
    if (jv < NPATCH)     pv0 = *(const uint4*)vb;
    if (jv + 1 < NPATCH) pv1 = *(const uint4*)(vb + 3 * DIM);
  };

  load_kv(0);

  float4v accO[4];
  #pragma unroll
  for (int j2 = 0; j2 < 4; ++j2) accO[j2] = (float4v){0.f, 0.f, 0.f, 0.f};
  float m_run[4] = {-1e30f, -1e30f, -1e30f, -1e30f};
  float lp[4] = {0.f, 0.f, 0.f, 0.f};

  constexpr int NIT = (NPATCH + 127) / 128;   // 8 slabs of 128 keys
  for (int it = 0; it < NIT; ++it) {
    if (it > 0) __syncthreads();
    {
      *(uint4*)&Ks[krow >> 6][krow & 63][kc0] = pk0;
      *(uint4*)&Ks[krow >> 6][krow & 63][kc0 + 8] = pk1;
      unsigned short va[8], vb8[8];
      *(uint4*)&va[0] = pv0;
      *(uint4*)&vb8[0] = pv1;
      const int vh = kp2 >> 5, lp2 = kp2 & 31;
      #pragma unroll
      for (int u = 0; u < 8; ++u) {
        unsigned pk = (unsigned)va[u] | ((unsigned)vb8[u] << 16);
        *(unsigned*)&Vt[vh][dg * 8 + u][2 * lp2] = pk;
      }
    }
    __syncthreads();
    if (it + 1 < NIT) load_kv((it + 1) * 128);

    const int j0 = it * 128 + half * 64;

    float4v s[4];
    __builtin_amdgcn_s_setprio(1);
    #pragma unroll
    for (int j = 0; j < 4; ++j) {
      s[j] = (float4v){0.f, 0.f, 0.f, 0.f};
      short8 bk0 = *(const short8*)&Ks[half][j * 16 + l16][quad * 8];
      short8 bk1 = *(const short8*)&Ks[half][j * 16 + l16][32 + quad * 8];
      s[j] = __builtin_amdgcn_mfma_f32_16x16x32_bf16(aq0, bk0, s[j], 0, 0, 0);
      s[j] = __builtin_amdgcn_mfma_f32_16x16x32_bf16(aq1, bk1, s[j], 0, 0, 0);
    }
    __builtin_amdgcn_s_setprio(0);

    // online softmax in exp2 units (s already scaled by log2e)
    float mx[4];
    #pragma unroll
    for (int r = 0; r < 4; ++r)
      mx[r] = fmaxf(fmaxf(s[0][r], s[1][r]), fmaxf(s[2][r], s[3][r]));
    #pragma unroll
    for (int mask = 1; mask < 16; mask <<= 1)
      #pragma unroll
      for (int r = 0; r < 4; ++r)
        mx[r] = fmaxf(mx[r], __shfl_xor(mx[r], mask));
    float gmax = fmaxf(fmaxf(mx[0] - m_run[0], mx[1] - m_run[1]),
                       fmaxf(mx[2] - m_run[2], mx[3] - m_run[3]));
    if (!__all(gmax <= 11.0f)) {   // defer-max: 11 bits ~ 7.6 nats
      #pragma unroll
      for (int r = 0; r < 4; ++r) {
        float mnew = fmaxf(m_run[r], mx[r]);
        float al = exp2f(m_run[r] - mnew);
        m_run[r] = mnew;
        lp[r] *= al;
        #pragma unroll
        for (int j2 = 0; j2 < 4; ++j2) accO[j2][r] *= al;
      }
    }
    #pragma unroll
    for (int j = 0; j < 4; ++j) {
      bool valid = (j0 + j * 16 + l16) < NPATCH;
      #pragma unroll
      for (int r = 0; r < 4; ++r) {
        float p = valid ? exp2f(s[j][r] - m_run[r]) : 0.f;
        lp[r] += p;
        Ps[wave][quad * 4 + r][j * 16 + l16] = f2bf(p);
      }
    }

    short8 pa0 = *(const short8*)&Ps[wave][l16][quad * 8];
    short8 pa1 = *(const short8*)&Ps[wave][l16][32 + quad * 8];
    __builtin_amdgcn_s_setprio(1);
    #pragma unroll
    for (int j2 = 0; j2 < 4; ++j2) {
      short8 v0 = *(const short8*)&Vt[half][j2 * 16 + l16][quad * 8];
      short8 v1 = *(const short8*)&Vt[half][j2 * 16 + l16][32 + quad * 8];
      accO[j2] = __builtin_amdgcn_mfma_f32_16x16x32_bf16(pa0, v0, accO[j2], 0, 0, 0);
      accO[j2] = __builtin_amdgcn_mfma_f32_16x16x32_bf16(pa1, v1, accO[j2], 0, 0, 0);
    }
    __builtin_amdgcn_s_setprio(0);
  }

  #pragma unroll
  for (int mask = 1; mask < 16; mask <<= 1)
    #pragma unroll
    for (int r = 0; r < 4; ++r)
      lp[r] += __shfl_xor(lp[r], mask);

  float* Pf = (float*)&Ps[0][0][0];
  __syncthreads();
  if (half == 1) {
    #pragma unroll
    for (int j2 = 0; j2 < 4; ++j2)
      #pragma unroll
      for (int r = 0; r < 4; ++r)
        Pf[((wq * 64 + lane) << 4) + j2 * 4 + r] = accO[j2][r];
    if (l16 == 0) {
      #pragma unroll
      for (int r = 0; r < 4; ++r) {
        Pf[4096 + ((wq * 16 + quad * 4 + r) << 1)]     = m_run[r];
        Pf[4096 + ((wq * 16 + quad * 4 + r) << 1) + 1] = lp[r];
      }
    }
  }
  __syncthreads();
  if (half == 0) {
    #pragma unroll
    for (int r = 0; r < 4; ++r) {
      float m1 = Pf[4096 + ((wq * 16 + quad * 4 + r) << 1)];
      float l1 = Pf[4096 + ((wq * 16 + quad * 4 + r) << 1) + 1];
      float M = fmaxf(m_run[r], m1);
      float w0 = exp2f(m_run[r] - M), w1 = exp2f(m1 - M);
      float inv = 1.f / (w0 * lp[r] + w1 * l1);
      int qi = qt0 + wq * 16 + quad * 4 + r;
      if (qi < NPATCH) {
        size_t off = (size_t)(b * NPATCH + qi) * DIM + h * HD + l16;
        #pragma unroll
        for (int j2 = 0; j2 < 4; ++j2) {
          float a1 = Pf[((wq * 64 + lane) << 4) + j2 * 4 + r];
          o[off + j2 * 16] = f2bf((w0 * accO[j2][r] + w1 * a1) * inv);
        }
      }
    }
  }
}

// ---------------------------------------------------------------------------
extern "C" void kernel_launch(void* const* d_in, const int* in_sizes, int n_in,
                              void* d_out, int out_size, void* d_ws, size_t ws_size,
                              hipStream_t stream) {
  const float* x      = (const float*)d_in[0];
  const float* W_emb  = (const float*)d_in[1];
  const float* b_emb  = (const float*)d_in[2];
  const float* ln1_g  = (const float*)d_in[3];
  const float* ln1_b  = (const float*)d_in[4];
  const float* W_qkv  = (const float*)d_in[5];
  const float* b_qkv  = (const float*)d_in[6];
  const float* W_proj = (const float*)d_in[7];
  const float* b_proj = (const float*)d_in[8];
  const float* ln2_g  = (const float*)d_in[9];
  const float* ln2_b  = (const float*)d_in[10];
  const float* W_mlp1 = (const float*)d_in[11];
  const float* b_mlp1 = (const float*)d_in[12];
  const float* W_mlp2 = (const float*)d_in[13];
  const float* b_mlp2 = (const float*)d_in[14];
  const float* lnf_g  = (const float*)d_in[15];
  const float* lnf_b  = (const float*)d_in[16];
  float* out = (float*)d_out;

  float* h              = (float*)d_ws;
  unsigned short* qkvb  = (unsigned short*)(h + (size_t)M_ROWS * DIM);
  unsigned short* midbf = qkvb;   // alias: qkvb dead after attn
  unsigned short* ybf   = qkvb + (size_t)M_ROWS * MLP_HID;
  unsigned short* obf   = ybf;    // alias: ybf dead after its GEMM
  unsigned short* wqkv_t  = ybf + (size_t)M_ROWS * DIM;
  unsigned short* wproj_t = wqkv_t  + (size_t)NLAYERS * DIM * 3 * DIM;
  unsigned short* wmlp1_t = wproj_t + (size_t)NLAYERS * DIM * DIM;
  unsigned short* wmlp2_t = wmlp1_t + (size_t)NLAYERS * DIM * MLP_HID;
  float2* rtab = (float2*)(wmlp2_t + (size_t)NLAYERS * MLP_HID * DIM);
  unsigned short* Pm    = (unsigned short*)(rtab + (size_t)NPATCH * 32);
  unsigned short* Wembt = Pm + (size_t)M_ROWS * KEMB;

  prep_kernel<<<dim3(PB6), 256, 0, stream>>>(
      W_qkv, wqkv_t, W_proj, wproj_t, W_mlp1, wmlp1_t, W_mlp2, wmlp2_t,
      x, Pm, W_emb, Wembt, rtab);

  const int LNG = (M_ROWS + 3) / 4;        // 1023
  // 1-D swizzled grids: nwg = (N/TN) * ceil(M/TM), all divisible by 8
  const int G64x64  = (DIM / 64) * 64;         // 512
  const int Gqkv    = (3 * DIM / 128) * 64;    // 768
  const int Gmlp1   = (MLP_HID / 128) * 32;    // 512

  // embed: out & h = Pm @ Wembt^T + b_emb  (64x64, BK=64)
  mfma_gemm<64, 64, 64, 5><<<dim3(G64x64), 256, 0, stream>>>(
      Pm, Wembt, b_emb, nullptr, out, h, nullptr, nullptr, M_ROWS, DIM, KEMB);

  for (int L = 0; L < NLAYERS; ++L) {
    ln_kernel<true><<<LNG, 256, 0, stream>>>(h, ln1_g + L * DIM, ln1_b + L * DIM, ybf, M_ROWS);
    // qkv with fused RoPE (64x128, BK=64: 8 iters, 48 KB LDS, 3 blk/CU)
    mfma_gemm<64, 128, 64, 6><<<dim3(Gqkv), 256, 0, stream>>>(
        ybf, wqkv_t + (size_t)L * DIM * 3 * DIM, b_qkv + L * 3 * DIM,
        nullptr, nullptr, nullptr, qkvb, rtab, M_ROWS, 3 * DIM, DIM);
    attn_kernel<<<dim3(512), 512, 0, stream>>>(qkvb, obf);
    // proj: h += o @ Wp + bias  (64x64, BK=64)
    mfma_gemm<64, 64, 64, 1><<<dim3(G64x64), 256, 0, stream>>>(
        obf, wproj_t + (size_t)L * DIM * DIM, b_proj + L * DIM,
        h, h, nullptr, nullptr, nullptr, M_ROWS, DIM, DIM);
    ln_kernel<true><<<LNG, 256, 0, stream>>>(h, ln2_g + L * DIM, ln2_b + L * DIM, ybf, M_ROWS);
    // mlp1 + GELU (128x128, BK=32)
    mfma_gemm<128, 128, 32, 2><<<dim3(Gmlp1), 256, 0, stream>>>(
        ybf, wmlp1_t + (size_t)L * DIM * MLP_HID, b_mlp1 + L * MLP_HID,
        nullptr, nullptr, nullptr, midbf, nullptr, M_ROWS, MLP_HID, DIM);
    // mlp2: h += mid @ Wm2 + bias  (64x64, BK=64)
    mfma_gemm<64, 64, 64, 1><<<dim3(G64x64), 256, 0, stream>>>(
        midbf, wmlp2_t + (size_t)L * MLP_HID * DIM, b_mlp2 + L * DIM,
        h, h, nullptr, nullptr, nullptr, M_ROWS, DIM, MLP_HID);
  }

  ln_kernel<false><<<LNG, 256, 0, stream>>>(h, lnf_g, lnf_b, out + (size_t)M_ROWS * DIM, M_ROWS);
}